// Round 7
// baseline (242.213 us; speedup 1.0000x reference)
//
#include <hip/hip_runtime.h>

namespace {

constexpr int kN = 2048;
constexpr int kWords = kN / 64;   // 32
constexpr int kC1 = 256;          // HEADS*HID
constexpr int kC2 = 64;           // OUT_CH
constexpr int kIN = 512;
constexpr float kNegSlope = 0.2f;
constexpr float kLnEps = 1e-5f;

__device__ __forceinline__ float leakyf(float v) {
  return v >= 0.f ? v : kNegSlope * v;
}
// online softmax accumulate (masked stream)
__device__ __forceinline__ void onl(float& m, float& l, float v) {
  if (v > m) { l = l * __expf(m - v) + 1.f; m = v; }
  else       { l += __expf(v - m); }
}
__device__ __forceinline__ void mergeml(float& M, float& L, float m, float l) {
  if (m > M) { L = L * __expf(M - m) + l; M = m; }
  else       { L += l * __expf(m - M); }
}

// ---------------- adjacency bitsets ----------------
__global__ void build_bits(const int* __restrict__ ei, int E,
                           unsigned long long* rowbits, unsigned long long* colbitsT) {
  int e = blockIdx.x * 256 + threadIdx.x;
  if (e >= E) return;
  int s = ei[e], d = ei[E + e];
  atomicOr(&rowbits[(size_t)s * kWords + (d >> 6)], 1ull << (d & 63));
  atomicOr(&colbitsT[(size_t)(s >> 6) * kN + d], 1ull << (s & 63));
}

// Fused per-row: A2 row s (counts via scatter) -> A2 structure (colbits2T)
// -> A3 row s = sum_k A2[s][k] * rowA[k] (via scatter) -> normalized motif.
// One block per s.
__global__ __launch_bounds__(256) void a3_motif(
    const unsigned long long* __restrict__ rowbits,
    float* __restrict__ motif,
    unsigned long long* __restrict__ colbits2T) {
  int s = blockIdx.x;
  int t = threadIdx.x;
  int lane = t & 63;
  __shared__ int cnt[kN];             // A2[s][k] counts (8 KB)
  __shared__ int sums[kN];            // A3[s][d] accumulators (8 KB)
  __shared__ unsigned short list[kN]; // jlist (phase1) then klist (phase3)
  __shared__ int n_total;
  __shared__ float redv[4];
  // zero cnt and sums
  reinterpret_cast<uint4*>(cnt)[t] = make_uint4(0u, 0u, 0u, 0u);
  reinterpret_cast<uint4*>(cnt)[t + 256] = make_uint4(0u, 0u, 0u, 0u);
  reinterpret_cast<uint4*>(sums)[t] = make_uint4(0u, 0u, 0u, 0u);
  reinterpret_cast<uint4*>(sums)[t + 256] = make_uint4(0u, 0u, 0u, 0u);
  __syncthreads();
  // decode out-neighbors j of s (wave 0) into list
  if (t < 64) {
    unsigned long long word = (lane < kWords) ? rowbits[(size_t)s * kWords + lane] : 0ull;
    int c = __popcll(word);
    int inc = c;
    for (int o = 1; o < 64; o <<= 1) { int v = __shfl_up(inc, o); if (lane >= o) inc += v; }
    if (lane == 63) n_total = inc;
    int off = inc - c;
    int base = lane * 64;
    while (word) {
      int b = __builtin_ctzll(word);
      word &= word - 1;
      list[off++] = (unsigned short)(base + b);
    }
  }
  __syncthreads();
  int jtot = n_total;
  // phase 1: cnt[k] += 1 for each j in rowA[s], k in rowA[j]  (flat scatter)
  for (int idx = t; idx < jtot * kWords; idx += 256) {
    int j = list[idx >> 5];
    int w = idx & (kWords - 1);
    unsigned long long word = rowbits[(size_t)j * kWords + w];
    int base = w * 64;
    while (word) {
      int b = __builtin_ctzll(word);
      word &= word - 1;
      atomicAdd(&cnt[base + b], 1);
    }
  }
  __syncthreads();
  // phase 2: klist = {k: cnt[k] > 0}; also write A2 structure bit (s, k)
  if (t < 64) {
    int base = lane * 32;
    unsigned int m = 0;
#pragma unroll
    for (int i = 0; i < 32; ++i) m |= (cnt[base + i] != 0 ? 1u : 0u) << i;
    int c = __popc(m);
    int inc = c;
    for (int o = 1; o < 64; o <<= 1) { int v = __shfl_up(inc, o); if (lane >= o) inc += v; }
    if (lane == 63) n_total = inc;
    int off = inc - c;
    unsigned int mm = m;
    while (mm) {
      int b = __builtin_ctz(mm);
      mm &= mm - 1;
      int k = base + b;
      list[off++] = (unsigned short)k;
      atomicOr(&colbits2T[(size_t)(s >> 6) * kN + k], 1ull << (s & 63));
    }
  }
  __syncthreads();
  int ktot = n_total;
  // phase 3: sums[d] += cnt[k] for each k in klist, d in rowA[k]  (flat scatter)
  for (int idx = t; idx < ktot * kWords; idx += 256) {
    int k = list[idx >> 5];
    int w = idx & (kWords - 1);
    unsigned long long word = rowbits[(size_t)k * kWords + w];
    int ck = cnt[k];
    int base = w * 64;
    while (word) {
      int b = __builtin_ctzll(word);
      word &= word - 1;
      atomicAdd(&sums[base + b], ck);
    }
  }
  __syncthreads();
  // phase 4: reduce row total, normalize, write motif row
  float tot = 0.f;
  int sv[8];
#pragma unroll
  for (int c = 0; c < 8; ++c) { sv[c] = sums[t + c * 256]; tot += (float)sv[c]; }
  for (int o = 32; o; o >>= 1) tot += __shfl_xor(tot, o);
  if (lane == 0) redv[t >> 6] = tot;
  __syncthreads();
  float inv = 1.f / fmaxf(redv[0] + redv[1] + redv[2] + redv[3], 1.f);
#pragma unroll
  for (int c = 0; c < 8; ++c)
    motif[(size_t)s * kN + t + c * 256] = (float)sv[c] * inv;
}

// C[z][M,Nn] = A[M,K] @ B_z[K,Nn]; B_z = z<nmain ? Bmain+z*K*Nn : Bx
__global__ __launch_bounds__(256) void gemm_batched(
    const float* __restrict__ A, const float* __restrict__ Bmain,
    const float* __restrict__ Bx, float* __restrict__ C,
    int M, int Nn, int K, int nmain) {
  int z = blockIdx.z;
  const float* B = (z < nmain) ? Bmain + (size_t)z * K * Nn : Bx;
  float* Cz = C + (size_t)z * M * Nn;
  __shared__ float As[16][65];
  __shared__ float Bs[16][65];
  int t = threadIdx.x;
  int tx = t & 15, ty = t >> 4;
  int row0 = blockIdx.y * 64, col0 = blockIdx.x * 64;
  float acc[4][4] = {};
  for (int k0 = 0; k0 < K; k0 += 16) {
    {
      int e = t * 4;
      int m = e >> 4, kk = e & 15;
      float4 va = *reinterpret_cast<const float4*>(A + (size_t)(row0 + m) * K + k0 + kk);
      As[kk + 0][m] = va.x; As[kk + 1][m] = va.y;
      As[kk + 2][m] = va.z; As[kk + 3][m] = va.w;
    }
    {
      int kb = t >> 4, nb = (t & 15) * 4;
      float4 vb = *reinterpret_cast<const float4*>(B + (size_t)(k0 + kb) * Nn + col0 + nb);
      Bs[kb][nb + 0] = vb.x; Bs[kb][nb + 1] = vb.y;
      Bs[kb][nb + 2] = vb.z; Bs[kb][nb + 3] = vb.w;
    }
    __syncthreads();
#pragma unroll
    for (int kk2 = 0; kk2 < 16; ++kk2) {
      float a[4], b[4];
#pragma unroll
      for (int i = 0; i < 4; ++i) a[i] = As[kk2][ty * 4 + i];
#pragma unroll
      for (int j = 0; j < 4; ++j) b[j] = Bs[kk2][tx * 4 + j];
#pragma unroll
      for (int i = 0; i < 4; ++i)
#pragma unroll
        for (int j = 0; j < 4; ++j) acc[i][j] += a[i] * b[j];
    }
    __syncthreads();
  }
  for (int i = 0; i < 4; ++i)
    for (int j = 0; j < 4; ++j)
      Cz[(size_t)(row0 + ty * 4 + i) * Nn + col0 + tx * 4 + j] = acc[i][j];
}

// s_src[hop,n,h], s_dst[hop,n,h]; block = H*64 threads; grid (N, 2)
template <int H>
__global__ void src_dst(const float* __restrict__ hopx,
                        const float* __restrict__ att_s,
                        const float* __restrict__ att_d,
                        float* __restrict__ ssrc, float* __restrict__ sdst) {
  int hop = blockIdx.y;
  int n = blockIdx.x;
  int t = threadIdx.x;
  int hh = t >> 6, c = t & 63;
  float xv = hopx[((size_t)hop * kN + n) * (H * 64) + t];
  float ps = xv * att_s[hop * H * 64 + hh * 64 + c];
  float pd = xv * att_d[hop * H * 64 + hh * 64 + c];
  for (int o = 32; o; o >>= 1) { ps += __shfl_xor(ps, o); pd += __shfl_xor(pd, o); }
  if (c == 0) {
    ssrc[((size_t)hop * kN + n) * H + hh] = ps;
    sdst[((size_t)hop * kN + n) * H + hh] = pd;
  }
}

// per (d,h): online-softmax stats over set bits of column mask.
// One wave per dst; lane l owns half of word l>>1. block 256; grid (N/4, 2)
template <int H>
__global__ __launch_bounds__(256) void stats_bits(
    const float* __restrict__ ssrc, const float* __restrict__ sdst,
    const float* __restrict__ motif,
    const unsigned long long* __restrict__ colbitsT,
    const unsigned long long* __restrict__ colbits2T,
    float* __restrict__ stats) {
  int hop = blockIdx.y;
  const unsigned long long* colmaskT = hop ? colbits2T : colbitsT;
  ssrc += (size_t)hop * kN * H;
  sdst += (size_t)hop * kN * H;
  stats += (size_t)hop * kN * H * 4;
  int wave = threadIdx.x >> 6, lane = threadIdx.x & 63;
  int d = blockIdx.x * 4 + wave;
  int w = lane >> 1, half = lane & 1;
  unsigned long long word = colmaskT[(size_t)w * kN + d];
  if (w == (d >> 6)) word |= 1ull << (d & 63);  // diagonal always masked-in
  unsigned int bits = (unsigned int)(word >> (half * 32));
  float sd[H];
#pragma unroll
  for (int h = 0; h < H; ++h) sd[h] = sdst[d * H + h];
  float m1[H], l1[H], m2[H], l2[H];
#pragma unroll
  for (int h = 0; h < H; ++h) { m1[h] = m2[h] = -3.0e38f; l1[h] = l2[h] = 0.f; }
  int base = w * 64 + half * 32;
  while (bits) {
    int b = __builtin_ctz(bits);
    bits &= bits - 1;
    int s = base + b;
    float mv = motif[(size_t)s * kN + d];
#pragma unroll
    for (int h = 0; h < H; ++h) {
      float v = ssrc[s * H + h] + sd[h];
      onl(m1[h], l1[h], leakyf(v));
      onl(m2[h], l2[h], leakyf(v * mv));
    }
  }
#pragma unroll
  for (int o = 1; o < 64; o <<= 1) {
#pragma unroll
    for (int h = 0; h < H; ++h) {
      float mm = __shfl_xor(m1[h], o), ll = __shfl_xor(l1[h], o);
      mergeml(m1[h], l1[h], mm, ll);
      float mm2 = __shfl_xor(m2[h], o), ll2 = __shfl_xor(l2[h], o);
      mergeml(m2[h], l2[h], mm2, ll2);
    }
  }
  if (lane == 0) {
#pragma unroll
    for (int h = 0; h < H; ++h) {
      float* sp = stats + ((size_t)d * H + h) * 4;
      sp[0] = m1[h]; sp[1] = 1.f / l1[h]; sp[2] = m2[h]; sp[3] = 1.f / l2[h];
    }
  }
}

// layer-1 aggregation: one dst per block (256 thr = 256 channels), both hops,
// sparse s-list from bitsets; fused bias + ELU. grid = N.
__global__ __launch_bounds__(256) void agg_l1(
    const float* __restrict__ hx,      // [2][N][256]
    const float* __restrict__ ssrc,    // [2][N][4]
    const float* __restrict__ sdst,    // [2][N][4]
    const float* __restrict__ motif,
    const unsigned long long* __restrict__ colbitsT,
    const unsigned long long* __restrict__ colbits2T,
    const float* __restrict__ stats,   // [2][N][4][4]
    const float* __restrict__ hop_att,
    const float* __restrict__ bias,
    float* __restrict__ hbuf) {
  int d = blockIdx.x;
  int t = threadIdx.x;
  int lane = t & 63;
  int h = t >> 6;
  __shared__ unsigned short slist[kN];
  __shared__ float w_lds[64 * 4];
  __shared__ int s_total;
  float a0 = hop_att[0], a1 = hop_att[1];
  float mxa = fmaxf(a0, a1);
  float e0 = __expf(a0 - mxa), e1 = __expf(a1 - mxa);
  float wh0 = e0 / (e0 + e1), wh1 = e1 / (e0 + e1);
  float acc = 0.f;
  for (int hop = 0; hop < 2; ++hop) {
    const unsigned long long* cm = hop ? colbits2T : colbitsT;
    if (t < 64) {
      unsigned long long word = (lane < kWords) ? cm[(size_t)lane * kN + d] : 0ull;
      if (lane == (d >> 6)) word |= 1ull << (d & 63);
      int cnt = __popcll(word);
      int inc = cnt;
      for (int o = 1; o < 64; o <<= 1) { int v = __shfl_up(inc, o); if (lane >= o) inc += v; }
      if (lane == 63) s_total = inc;
      int off = inc - cnt;
      int base = lane * 64;
      while (word) {
        int b = __builtin_ctzll(word);
        word &= word - 1;
        slist[off++] = (unsigned short)(base + b);
      }
    }
    __syncthreads();
    int total = s_total;
    float sd = sdst[((size_t)hop * kN + d) * 4 + h];
    const float* sp = &stats[(((size_t)hop * kN + d) * 4 + h) * 4];
    float m1 = sp[0], il1 = sp[1], m2 = sp[2], il2 = sp[3];
    float wh = hop ? wh1 : wh0;
    const float* hxp = hx + (size_t)hop * kN * kC1;
    const float* ssp = ssrc + (size_t)hop * kN * 4;
    for (int c0 = 0; c0 < total; c0 += 64) {
      int nsi = min(64, total - c0);
      int si = lane;
      if (si < nsi) {
        int s = slist[c0 + si];
        float mv = motif[(size_t)s * kN + d];
        float v = ssp[s * 4 + h] + sd;
        w_lds[si * 4 + h] = (0.5f * __expf(leakyf(v) - m1) * il1 +
                             0.5f * __expf(leakyf(v * mv) - m2) * il2) * wh;
      }
      __syncthreads();
      for (int q = 0; q < nsi; ++q) {
        int s = slist[c0 + q];
        acc += w_lds[q * 4 + h] * hxp[(size_t)s * kC1 + t];
      }
      __syncthreads();
    }
    __syncthreads();
  }
  acc += bias[t];
  hbuf[(size_t)d * kC1 + t] = acc > 0.f ? acc : __expf(acc) - 1.f;
}

// layer-2 aggregation: one dst per block, 4 si-subgroups x 64 channels;
// fused residual + LayerNorm + bias -> final output. grid = N.
__global__ __launch_bounds__(256) void agg_l2(
    const float* __restrict__ hx,      // [2][N][64]
    const float* __restrict__ ssrc,    // [2][N]
    const float* __restrict__ sdst,    // [2][N]
    const float* __restrict__ motif,
    const unsigned long long* __restrict__ colbitsT,
    const unsigned long long* __restrict__ colbits2T,
    const float* __restrict__ stats,   // [2][N][4]
    const float* __restrict__ hop_att,
    const float* __restrict__ res,     // [N][64]
    const float* __restrict__ lns, const float* __restrict__ lnb,
    const float* __restrict__ l2b,
    float* __restrict__ out) {
  int d = blockIdx.x;
  int t = threadIdx.x;
  int lane = t & 63;   // channel
  int g = t >> 6;      // si-subgroup
  __shared__ unsigned short slist[kN];
  __shared__ float w_lds[64];
  __shared__ int s_total;
  __shared__ float red[4][64];
  float a0 = hop_att[0], a1 = hop_att[1];
  float mxa = fmaxf(a0, a1);
  float e0 = __expf(a0 - mxa), e1 = __expf(a1 - mxa);
  float wh0 = e0 / (e0 + e1), wh1 = e1 / (e0 + e1);
  float acc = 0.f;
  for (int hop = 0; hop < 2; ++hop) {
    const unsigned long long* cm = hop ? colbits2T : colbitsT;
    if (t < 64) {
      unsigned long long word = (lane < kWords) ? cm[(size_t)lane * kN + d] : 0ull;
      if (lane == (d >> 6)) word |= 1ull << (d & 63);
      int cnt = __popcll(word);
      int inc = cnt;
      for (int o = 1; o < 64; o <<= 1) { int v = __shfl_up(inc, o); if (lane >= o) inc += v; }
      if (lane == 63) s_total = inc;
      int off = inc - cnt;
      int base = lane * 64;
      while (word) {
        int b = __builtin_ctzll(word);
        word &= word - 1;
        slist[off++] = (unsigned short)(base + b);
      }
    }
    __syncthreads();
    int total = s_total;
    float sd = sdst[(size_t)hop * kN + d];
    const float* sp = &stats[((size_t)hop * kN + d) * 4];
    float m1 = sp[0], il1 = sp[1], m2 = sp[2], il2 = sp[3];
    float wh = hop ? wh1 : wh0;
    const float* hxp = hx + (size_t)hop * kN * kC2;
    const float* ssp = ssrc + (size_t)hop * kN;
    for (int c0 = 0; c0 < total; c0 += 64) {
      int nsi = min(64, total - c0);
      if (t < nsi) {
        int s = slist[c0 + t];
        float mv = motif[(size_t)s * kN + d];
        float v = ssp[s] + sd;
        w_lds[t] = (0.5f * __expf(leakyf(v) - m1) * il1 +
                    0.5f * __expf(leakyf(v * mv) - m2) * il2) * wh;
      }
      __syncthreads();
      for (int q = g; q < nsi; q += 4) {
        int s = slist[c0 + q];
        acc += w_lds[q] * hxp[(size_t)s * kC2 + lane];
      }
      __syncthreads();
    }
    __syncthreads();
  }
  red[g][lane] = acc;
  __syncthreads();
  if (t < 64) {
    float v = red[0][t] + red[1][t] + red[2][t] + red[3][t] + res[(size_t)d * kC2 + t];
    float s = v;
    for (int o = 32; o; o >>= 1) s += __shfl_xor(s, o);
    float mu = s * (1.f / kC2);
    float dv = v - mu;
    float q = dv * dv;
    for (int o = 32; o; o >>= 1) q += __shfl_xor(q, o);
    float var = q * (1.f / kC2);
    out[(size_t)d * kC2 + t] = dv * rsqrtf(var + kLnEps) * lns[t] + lnb[t] + l2b[t];
  }
}

}  // namespace

extern "C" void kernel_launch(void* const* d_in, const int* in_sizes, int n_in,
                              void* d_out, int out_size, void* d_ws, size_t ws_size,
                              hipStream_t stream) {
  const float* x    = (const float*)d_in[0];
  const int*   ei   = (const int*)d_in[1];
  const float* l1w  = (const float*)d_in[2];
  const float* l1as = (const float*)d_in[3];
  const float* l1ad = (const float*)d_in[4];
  const float* l1ha = (const float*)d_in[5];
  const float* l1b  = (const float*)d_in[6];
  const float* l2w  = (const float*)d_in[7];
  const float* l2as = (const float*)d_in[8];
  const float* l2ad = (const float*)d_in[9];
  const float* l2ha = (const float*)d_in[10];
  const float* l2rw = (const float*)d_in[11];
  const float* lns  = (const float*)d_in[12];
  const float* lnb  = (const float*)d_in[13];
  const float* l2b  = (const float*)d_in[14];
  int E = in_sizes[1] / 2;

  // ---- workspace layout (bytes) ----
  size_t o = 0;
  auto take = [&](size_t bytes) { size_t r = o; o += (bytes + 255) & ~(size_t)255; return r; };
  size_t oRB  = take((size_t)kN * kWords * 8);      // rowbits
  size_t oCB  = take((size_t)kWords * kN * 8);      // colbitsT
  size_t oCB2 = take((size_t)kWords * kN * 8);      // colbits2T (A2 structure)
  size_t zEnd = o;                                  // zero region end
  size_t oMF  = take((size_t)kN * kN * 4);
  size_t oHX1 = take((size_t)2 * kN * kC1 * 4);
  size_t oH   = take((size_t)kN * kC1 * 4);
  size_t oHX2 = take((size_t)3 * kN * kC2 * 4);     // hop0 | hop1 | res
  size_t oSS1 = take((size_t)2 * kN * 4 * 4);
  size_t oSD1 = take((size_t)2 * kN * 4 * 4);
  size_t oSS2 = take((size_t)2 * kN * 4);
  size_t oSD2 = take((size_t)2 * kN * 4);
  size_t oST1 = take((size_t)2 * kN * 4 * 4 * 4);
  size_t oST2 = take((size_t)2 * kN * 4 * 4);
  if (ws_size < o) return;  // insufficient scratch; fail visibly

  char* w = (char*)d_ws;
  unsigned long long* rowbits = (unsigned long long*)(w + oRB);
  unsigned long long* colbitsT = (unsigned long long*)(w + oCB);
  unsigned long long* colbits2T = (unsigned long long*)(w + oCB2);
  float* motif = (float*)(w + oMF);
  float* hx1 = (float*)(w + oHX1);
  float* hbuf = (float*)(w + oH);
  float* hx2 = (float*)(w + oHX2);
  float* res = hx2 + (size_t)2 * kN * kC2;
  float* ss1 = (float*)(w + oSS1);
  float* sd1 = (float*)(w + oSD1);
  float* ss2 = (float*)(w + oSS2);
  float* sd2 = (float*)(w + oSD2);
  float* st1 = (float*)(w + oST1);
  float* st2 = (float*)(w + oST2);

  hipMemsetAsync(d_ws, 0, zEnd, stream);

  build_bits<<<(E + 255) / 256, 256, 0, stream>>>(ei, E, rowbits, colbitsT);
  a3_motif<<<kN, 256, 0, stream>>>(rowbits, motif, colbits2T);

  // ---- layer 1 (H=4, C=64, concat) ----
  gemm_batched<<<dim3(kC1 / 64, kN / 64, 2), 256, 0, stream>>>(
      x, l1w, l1w, hx1, kN, kC1, kIN, 2);
  src_dst<4><<<dim3(kN, 2), 256, 0, stream>>>(hx1, l1as, l1ad, ss1, sd1);
  stats_bits<4><<<dim3(kN / 4, 2), 256, 0, stream>>>(
      ss1, sd1, motif, colbitsT, colbits2T, st1);
  agg_l1<<<kN, 256, 0, stream>>>(hx1, ss1, sd1, motif, colbitsT, colbits2T,
                                 st1, l1ha, l1b, hbuf);

  // ---- layer 2 (H=1, C=64, residual + LN) ----
  gemm_batched<<<dim3(1, kN / 64, 3), 256, 0, stream>>>(
      hbuf, l2w, l2rw, hx2, kN, kC2, kC1, 2);
  src_dst<1><<<dim3(kN, 2), 64, 0, stream>>>(hx2, l2as, l2ad, ss2, sd2);
  stats_bits<1><<<dim3(kN / 4, 2), 256, 0, stream>>>(
      ss2, sd2, motif, colbitsT, colbits2T, st2);
  agg_l2<<<kN, 256, 0, stream>>>(hx2, ss2, sd2, motif, colbitsT, colbits2T,
                                 st2, l2ha, res, lns, lnb, l2b, (float*)d_out);
}

// Round 8
// 234.353 us; speedup vs baseline: 1.0335x; 1.0335x over previous
//
#include <hip/hip_runtime.h>

namespace {

constexpr int kN = 2048;
constexpr int kWords = kN / 64;   // 32
constexpr int kC1 = 256;          // HEADS*HID
constexpr int kC2 = 64;           // OUT_CH
constexpr int kIN = 512;
constexpr float kNegSlope = 0.2f;
constexpr float kLnEps = 1e-5f;

__device__ __forceinline__ float leakyf(float v) {
  return v >= 0.f ? v : kNegSlope * v;
}
// online softmax accumulate (masked stream)
__device__ __forceinline__ void onl(float& m, float& l, float v) {
  if (v > m) { l = l * __expf(m - v) + 1.f; m = v; }
  else       { l += __expf(v - m); }
}
__device__ __forceinline__ void mergeml(float& M, float& L, float m, float l) {
  if (m > M) { L = L * __expf(M - m) + l; M = m; }
  else       { L += l * __expf(m - M); }
}

// ---------------- adjacency bitsets ----------------
__global__ void build_bits(const int* __restrict__ ei, int E,
                           unsigned long long* rowbits, unsigned long long* colbitsT) {
  int e = blockIdx.x * 256 + threadIdx.x;
  if (e >= E) return;
  int s = ei[e], d = ei[E + e];
  atomicOr(&rowbits[(size_t)s * kWords + (d >> 6)], 1ull << (d & 63));
  atomicOr(&colbitsT[(size_t)(s >> 6) * kN + d], 1ull << (s & 63));
}

// Fused per-row: A2 row s (u16-packed counts via scatter) -> A2 structure
// (colbits2T) -> A3 row s = sum_k A2[s][k]*rowA[k] (scatter) -> motif row.
// Counts bounded by max-degree^2 (< 65536) so u16 halves never carry.
__global__ __launch_bounds__(256) void a3_motif(
    const unsigned long long* __restrict__ rowbits,
    float* __restrict__ motif,
    unsigned long long* __restrict__ colbits2T) {
  int s = blockIdx.x;
  int t = threadIdx.x;
  int lane = t & 63;
  __shared__ unsigned int cntp[kN / 2];   // packed u16 A2[s][k] (4 KB)
  __shared__ unsigned int sumsp[kN / 2];  // packed u16 A3[s][d] (4 KB)
  __shared__ unsigned short list[kN];     // jlist then klist (4 KB)
  __shared__ int n_total;
  __shared__ float redv[4];
  reinterpret_cast<uint4*>(cntp)[t] = make_uint4(0u, 0u, 0u, 0u);
  reinterpret_cast<uint4*>(sumsp)[t] = make_uint4(0u, 0u, 0u, 0u);
  __syncthreads();
  // decode out-neighbors j of s (wave 0) into list
  if (t < 64) {
    unsigned long long word = (lane < kWords) ? rowbits[(size_t)s * kWords + lane] : 0ull;
    int c = __popcll(word);
    int inc = c;
    for (int o = 1; o < 64; o <<= 1) { int v = __shfl_up(inc, o); if (lane >= o) inc += v; }
    if (lane == 63) n_total = inc;
    int off = inc - c;
    int base = lane * 64;
    while (word) {
      int b = __builtin_ctzll(word);
      word &= word - 1;
      list[off++] = (unsigned short)(base + b);
    }
  }
  __syncthreads();
  int jtot = n_total;
  int wsel = t & 31;          // word index is loop-invariant (strides % 32 == 0)
  int baseh = wsel << 5;      // (wsel*64)/2 : packed-word base for this word
  // phase 1: cnt[k] += 1 for each j in rowA[s], k in rowA[j]  (2-deep MLP)
  int tot1 = jtot * kWords;
  for (int idx = t; idx < tot1; idx += 512) {
    unsigned long long w1 = rowbits[(size_t)list[idx >> 5] * kWords + wsel];
    unsigned long long w2 = 0;
    if (idx + 256 < tot1)
      w2 = rowbits[(size_t)list[(idx + 256) >> 5] * kWords + wsel];
    while (w1) {
      int b = __builtin_ctzll(w1); w1 &= w1 - 1;
      atomicAdd(&cntp[baseh + (b >> 1)], 1u << ((b & 1) * 16));
    }
    while (w2) {
      int b = __builtin_ctzll(w2); w2 &= w2 - 1;
      atomicAdd(&cntp[baseh + (b >> 1)], 1u << ((b & 1) * 16));
    }
  }
  __syncthreads();
  // phase 2: klist = {k: cnt[k] > 0}; also write A2 structure bit (s, k)
  if (t < 64) {
    int kb = lane * 32;
    unsigned int m = 0;
#pragma unroll
    for (int i2 = 0; i2 < 16; ++i2) {
      unsigned int pw = cntp[(kb >> 1) + i2];
      if (pw & 0xffffu) m |= 1u << (2 * i2);
      if (pw >> 16)     m |= 1u << (2 * i2 + 1);
    }
    int c = __popc(m);
    int inc = c;
    for (int o = 1; o < 64; o <<= 1) { int v = __shfl_up(inc, o); if (lane >= o) inc += v; }
    if (lane == 63) n_total = inc;
    int off = inc - c;
    while (m) {
      int b = __builtin_ctz(m);
      m &= m - 1;
      int k = kb + b;
      list[off++] = (unsigned short)k;
      atomicOr(&colbits2T[(size_t)(s >> 6) * kN + k], 1ull << (s & 63));
    }
  }
  __syncthreads();
  int ktot = n_total;
  // phase 3: sums[d] += cnt[k] for each k in klist, d in rowA[k]  (4-deep MLP)
  int tot3 = ktot * kWords;
  for (int idx = t; idx < tot3; idx += 1024) {
    unsigned long long wd[4];
    int kk[4];
#pragma unroll
    for (int u = 0; u < 4; ++u) {
      int id = idx + u * 256;
      if (id < tot3) {
        kk[u] = list[id >> 5];
        wd[u] = rowbits[(size_t)kk[u] * kWords + wsel];
      } else { kk[u] = 0; wd[u] = 0ull; }
    }
#pragma unroll
    for (int u = 0; u < 4; ++u) {
      unsigned long long word = wd[u];
      if (!word) continue;
      unsigned int cp = cntp[kk[u] >> 1];
      unsigned int ck = (cp >> ((kk[u] & 1) * 16)) & 0xffffu;
      while (word) {
        int b = __builtin_ctzll(word); word &= word - 1;
        atomicAdd(&sumsp[baseh + (b >> 1)], ck << ((b & 1) * 16));
      }
    }
  }
  __syncthreads();
  // phase 4: reduce row total, normalize, write motif row
  float tot = 0.f;
  float sv[8];
#pragma unroll
  for (int c = 0; c < 8; ++c) {
    int d = t + c * 256;
    sv[c] = (float)((sumsp[d >> 1] >> ((d & 1) * 16)) & 0xffffu);
    tot += sv[c];
  }
  for (int o = 32; o; o >>= 1) tot += __shfl_xor(tot, o);
  if (lane == 0) redv[t >> 6] = tot;
  __syncthreads();
  float inv = 1.f / fmaxf(redv[0] + redv[1] + redv[2] + redv[3], 1.f);
#pragma unroll
  for (int c = 0; c < 8; ++c)
    motif[(size_t)s * kN + t + c * 256] = sv[c] * inv;
}

// C[z][M,Nn] = A[M,K] @ B_z[K,Nn]; B_z = z<nmain ? Bmain+z*K*Nn : Bx
__global__ __launch_bounds__(256) void gemm_batched(
    const float* __restrict__ A, const float* __restrict__ Bmain,
    const float* __restrict__ Bx, float* __restrict__ C,
    int M, int Nn, int K, int nmain) {
  int z = blockIdx.z;
  const float* B = (z < nmain) ? Bmain + (size_t)z * K * Nn : Bx;
  float* Cz = C + (size_t)z * M * Nn;
  __shared__ float As[16][65];
  __shared__ float Bs[16][65];
  int t = threadIdx.x;
  int tx = t & 15, ty = t >> 4;
  int row0 = blockIdx.y * 64, col0 = blockIdx.x * 64;
  float acc[4][4] = {};
  for (int k0 = 0; k0 < K; k0 += 16) {
    {
      int e = t * 4;
      int m = e >> 4, kk = e & 15;
      float4 va = *reinterpret_cast<const float4*>(A + (size_t)(row0 + m) * K + k0 + kk);
      As[kk + 0][m] = va.x; As[kk + 1][m] = va.y;
      As[kk + 2][m] = va.z; As[kk + 3][m] = va.w;
    }
    {
      int kb = t >> 4, nb = (t & 15) * 4;
      float4 vb = *reinterpret_cast<const float4*>(B + (size_t)(k0 + kb) * Nn + col0 + nb);
      Bs[kb][nb + 0] = vb.x; Bs[kb][nb + 1] = vb.y;
      Bs[kb][nb + 2] = vb.z; Bs[kb][nb + 3] = vb.w;
    }
    __syncthreads();
#pragma unroll
    for (int kk2 = 0; kk2 < 16; ++kk2) {
      float a[4], b[4];
#pragma unroll
      for (int i = 0; i < 4; ++i) a[i] = As[kk2][ty * 4 + i];
#pragma unroll
      for (int j = 0; j < 4; ++j) b[j] = Bs[kk2][tx * 4 + j];
#pragma unroll
      for (int i = 0; i < 4; ++i)
#pragma unroll
        for (int j = 0; j < 4; ++j) acc[i][j] += a[i] * b[j];
    }
    __syncthreads();
  }
  for (int i = 0; i < 4; ++i)
    for (int j = 0; j < 4; ++j)
      Cz[(size_t)(row0 + ty * 4 + i) * Nn + col0 + tx * 4 + j] = acc[i][j];
}

// s_src[hop,n,h], s_dst[hop,n,h]; block = H*64 threads; grid (N, 2)
template <int H>
__global__ void src_dst(const float* __restrict__ hopx,
                        const float* __restrict__ att_s,
                        const float* __restrict__ att_d,
                        float* __restrict__ ssrc, float* __restrict__ sdst) {
  int hop = blockIdx.y;
  int n = blockIdx.x;
  int t = threadIdx.x;
  int hh = t >> 6, c = t & 63;
  float xv = hopx[((size_t)hop * kN + n) * (H * 64) + t];
  float ps = xv * att_s[hop * H * 64 + hh * 64 + c];
  float pd = xv * att_d[hop * H * 64 + hh * 64 + c];
  for (int o = 32; o; o >>= 1) { ps += __shfl_xor(ps, o); pd += __shfl_xor(pd, o); }
  if (c == 0) {
    ssrc[((size_t)hop * kN + n) * H + hh] = ps;
    sdst[((size_t)hop * kN + n) * H + hh] = pd;
  }
}

// per (d,h): online-softmax stats over set bits of column mask, with a
// one-deep gather-prefetch pipeline. One wave per dst. block 256; grid (N/4,2)
template <int H>
__global__ __launch_bounds__(256) void stats_bits(
    const float* __restrict__ ssrc, const float* __restrict__ sdst,
    const float* __restrict__ motif,
    const unsigned long long* __restrict__ colbitsT,
    const unsigned long long* __restrict__ colbits2T,
    float* __restrict__ stats) {
  int hop = blockIdx.y;
  const unsigned long long* colmaskT = hop ? colbits2T : colbitsT;
  ssrc += (size_t)hop * kN * H;
  sdst += (size_t)hop * kN * H;
  stats += (size_t)hop * kN * H * 4;
  int wave = threadIdx.x >> 6, lane = threadIdx.x & 63;
  int d = blockIdx.x * 4 + wave;
  int w = lane >> 1, half = lane & 1;
  unsigned long long word = colmaskT[(size_t)w * kN + d];
  if (w == (d >> 6)) word |= 1ull << (d & 63);  // diagonal always masked-in
  unsigned int bits = (unsigned int)(word >> (half * 32));
  float sd[H];
#pragma unroll
  for (int h = 0; h < H; ++h) sd[h] = sdst[d * H + h];
  float m1[H], l1v[H], m2[H], l2v[H];
#pragma unroll
  for (int h = 0; h < H; ++h) { m1[h] = m2[h] = -3.0e38f; l1v[h] = l2v[h] = 0.f; }
  int base = w * 64 + half * 32;
  // prefetch first neighbor
  int sA = -1; float mvA = 0.f; float svA[H] = {};
  if (bits) {
    int b = __builtin_ctz(bits); bits &= bits - 1; sA = base + b;
    mvA = motif[(size_t)sA * kN + d];
    if constexpr (H == 4) {
      float4 v = reinterpret_cast<const float4*>(ssrc)[sA];
      svA[0] = v.x; svA[1] = v.y; svA[2] = v.z; svA[3] = v.w;
    } else {
      svA[0] = ssrc[sA];
    }
  }
  while (sA >= 0) {
    int sB = -1; float mvB = 0.f; float svB[H] = {};
    if (bits) {
      int b = __builtin_ctz(bits); bits &= bits - 1; sB = base + b;
      mvB = motif[(size_t)sB * kN + d];
      if constexpr (H == 4) {
        float4 v = reinterpret_cast<const float4*>(ssrc)[sB];
        svB[0] = v.x; svB[1] = v.y; svB[2] = v.z; svB[3] = v.w;
      } else {
        svB[0] = ssrc[sB];
      }
    }
#pragma unroll
    for (int h = 0; h < H; ++h) {
      float v = svA[h] + sd[h];
      onl(m1[h], l1v[h], leakyf(v));
      onl(m2[h], l2v[h], leakyf(v * mvA));
    }
    sA = sB; mvA = mvB;
#pragma unroll
    for (int h = 0; h < H; ++h) svA[h] = svB[h];
  }
#pragma unroll
  for (int o = 1; o < 64; o <<= 1) {
#pragma unroll
    for (int h = 0; h < H; ++h) {
      float mm = __shfl_xor(m1[h], o), ll = __shfl_xor(l1v[h], o);
      mergeml(m1[h], l1v[h], mm, ll);
      float mm2 = __shfl_xor(m2[h], o), ll2 = __shfl_xor(l2v[h], o);
      mergeml(m2[h], l2v[h], mm2, ll2);
    }
  }
  if (lane == 0) {
#pragma unroll
    for (int h = 0; h < H; ++h) {
      float* sp = stats + ((size_t)d * H + h) * 4;
      sp[0] = m1[h]; sp[1] = 1.f / l1v[h]; sp[2] = m2[h]; sp[3] = 1.f / l2v[h];
    }
  }
}

// layer-1 aggregation: one dst per block (256 thr = 256 channels), both hops,
// sparse s-list; 4-way unrolled row-FMA; fused bias + ELU. grid = N.
__global__ __launch_bounds__(256) void agg_l1(
    const float* __restrict__ hx,      // [2][N][256]
    const float* __restrict__ ssrc,    // [2][N][4]
    const float* __restrict__ sdst,    // [2][N][4]
    const float* __restrict__ motif,
    const unsigned long long* __restrict__ colbitsT,
    const unsigned long long* __restrict__ colbits2T,
    const float* __restrict__ stats,   // [2][N][4][4]
    const float* __restrict__ hop_att,
    const float* __restrict__ bias,
    float* __restrict__ hbuf) {
  int d = blockIdx.x;
  int t = threadIdx.x;
  int lane = t & 63;
  int h = t >> 6;
  __shared__ unsigned short slist[kN];
  __shared__ float w_lds[64 * 4];
  __shared__ int s_total;
  float a0 = hop_att[0], a1 = hop_att[1];
  float mxa = fmaxf(a0, a1);
  float e0 = __expf(a0 - mxa), e1 = __expf(a1 - mxa);
  float wh0 = e0 / (e0 + e1), wh1 = e1 / (e0 + e1);
  float acc = 0.f;
  for (int hop = 0; hop < 2; ++hop) {
    const unsigned long long* cm = hop ? colbits2T : colbitsT;
    if (t < 64) {
      unsigned long long word = (lane < kWords) ? cm[(size_t)lane * kN + d] : 0ull;
      if (lane == (d >> 6)) word |= 1ull << (d & 63);
      int cnt = __popcll(word);
      int inc = cnt;
      for (int o = 1; o < 64; o <<= 1) { int v = __shfl_up(inc, o); if (lane >= o) inc += v; }
      if (lane == 63) s_total = inc;
      int off = inc - cnt;
      int base = lane * 64;
      while (word) {
        int b = __builtin_ctzll(word);
        word &= word - 1;
        slist[off++] = (unsigned short)(base + b);
      }
    }
    __syncthreads();
    int total = s_total;
    float sd = sdst[((size_t)hop * kN + d) * 4 + h];
    const float* sp = &stats[(((size_t)hop * kN + d) * 4 + h) * 4];
    float m1 = sp[0], il1 = sp[1], m2 = sp[2], il2 = sp[3];
    float wh = hop ? wh1 : wh0;
    const float* hxp = hx + (size_t)hop * kN * kC1;
    const float* ssp = ssrc + (size_t)hop * kN * 4;
    for (int c0 = 0; c0 < total; c0 += 64) {
      int nsi = min(64, total - c0);
      if (lane < nsi) {
        int s = slist[c0 + lane];
        float mv = motif[(size_t)s * kN + d];
        float v = ssp[s * 4 + h] + sd;
        w_lds[lane * 4 + h] = (0.5f * __expf(leakyf(v) - m1) * il1 +
                               0.5f * __expf(leakyf(v * mv) - m2) * il2) * wh;
      }
      __syncthreads();
      int q = 0;
      for (; q + 4 <= nsi; q += 4) {
        int s0 = slist[c0 + q + 0], s1 = slist[c0 + q + 1];
        int s2 = slist[c0 + q + 2], s3 = slist[c0 + q + 3];
        float r0 = hxp[(size_t)s0 * kC1 + t];
        float r1 = hxp[(size_t)s1 * kC1 + t];
        float r2 = hxp[(size_t)s2 * kC1 + t];
        float r3 = hxp[(size_t)s3 * kC1 + t];
        acc += w_lds[(q + 0) * 4 + h] * r0 + w_lds[(q + 1) * 4 + h] * r1 +
               w_lds[(q + 2) * 4 + h] * r2 + w_lds[(q + 3) * 4 + h] * r3;
      }
      for (; q < nsi; ++q) {
        int s = slist[c0 + q];
        acc += w_lds[q * 4 + h] * hxp[(size_t)s * kC1 + t];
      }
      __syncthreads();
    }
    __syncthreads();
  }
  acc += bias[t];
  hbuf[(size_t)d * kC1 + t] = acc > 0.f ? acc : __expf(acc) - 1.f;
}

// layer-2 aggregation: one dst per block, 4 si-subgroups x 64 channels;
// 2-way unrolled; fused residual + LayerNorm + bias -> output. grid = N.
__global__ __launch_bounds__(256) void agg_l2(
    const float* __restrict__ hx,      // [2][N][64]
    const float* __restrict__ ssrc,    // [2][N]
    const float* __restrict__ sdst,    // [2][N]
    const float* __restrict__ motif,
    const unsigned long long* __restrict__ colbitsT,
    const unsigned long long* __restrict__ colbits2T,
    const float* __restrict__ stats,   // [2][N][4]
    const float* __restrict__ hop_att,
    const float* __restrict__ res,     // [N][64]
    const float* __restrict__ lns, const float* __restrict__ lnb,
    const float* __restrict__ l2b,
    float* __restrict__ out) {
  int d = blockIdx.x;
  int t = threadIdx.x;
  int lane = t & 63;   // channel
  int g = t >> 6;      // si-subgroup
  __shared__ unsigned short slist[kN];
  __shared__ float w_lds[64];
  __shared__ int s_total;
  __shared__ float red[4][64];
  float a0 = hop_att[0], a1 = hop_att[1];
  float mxa = fmaxf(a0, a1);
  float e0 = __expf(a0 - mxa), e1 = __expf(a1 - mxa);
  float wh0 = e0 / (e0 + e1), wh1 = e1 / (e0 + e1);
  float acc = 0.f;
  for (int hop = 0; hop < 2; ++hop) {
    const unsigned long long* cm = hop ? colbits2T : colbitsT;
    if (t < 64) {
      unsigned long long word = (lane < kWords) ? cm[(size_t)lane * kN + d] : 0ull;
      if (lane == (d >> 6)) word |= 1ull << (d & 63);
      int cnt = __popcll(word);
      int inc = cnt;
      for (int o = 1; o < 64; o <<= 1) { int v = __shfl_up(inc, o); if (lane >= o) inc += v; }
      if (lane == 63) s_total = inc;
      int off = inc - cnt;
      int base = lane * 64;
      while (word) {
        int b = __builtin_ctzll(word);
        word &= word - 1;
        slist[off++] = (unsigned short)(base + b);
      }
    }
    __syncthreads();
    int total = s_total;
    float sd = sdst[(size_t)hop * kN + d];
    const float* sp = &stats[((size_t)hop * kN + d) * 4];
    float m1 = sp[0], il1 = sp[1], m2 = sp[2], il2 = sp[3];
    float wh = hop ? wh1 : wh0;
    const float* hxp = hx + (size_t)hop * kN * kC2;
    const float* ssp = ssrc + (size_t)hop * kN;
    for (int c0 = 0; c0 < total; c0 += 64) {
      int nsi = min(64, total - c0);
      if (t < nsi) {
        int s = slist[c0 + t];
        float mv = motif[(size_t)s * kN + d];
        float v = ssp[s] + sd;
        w_lds[t] = (0.5f * __expf(leakyf(v) - m1) * il1 +
                    0.5f * __expf(leakyf(v * mv) - m2) * il2) * wh;
      }
      __syncthreads();
      int q = g;
      for (; q + 4 < nsi; q += 8) {
        int s0 = slist[c0 + q], s1 = slist[c0 + q + 4];
        float r0 = hxp[(size_t)s0 * kC2 + lane];
        float r1 = hxp[(size_t)s1 * kC2 + lane];
        acc += w_lds[q] * r0 + w_lds[q + 4] * r1;
      }
      if (q < nsi) {
        int s0 = slist[c0 + q];
        acc += w_lds[q] * hxp[(size_t)s0 * kC2 + lane];
      }
      __syncthreads();
    }
    __syncthreads();
  }
  red[g][lane] = acc;
  __syncthreads();
  if (t < 64) {
    float v = red[0][t] + red[1][t] + red[2][t] + red[3][t] + res[(size_t)d * kC2 + t];
    float s = v;
    for (int o = 32; o; o >>= 1) s += __shfl_xor(s, o);
    float mu = s * (1.f / kC2);
    float dv = v - mu;
    float q = dv * dv;
    for (int o = 32; o; o >>= 1) q += __shfl_xor(q, o);
    float var = q * (1.f / kC2);
    out[(size_t)d * kC2 + t] = dv * rsqrtf(var + kLnEps) * lns[t] + lnb[t] + l2b[t];
  }
}

}  // namespace

extern "C" void kernel_launch(void* const* d_in, const int* in_sizes, int n_in,
                              void* d_out, int out_size, void* d_ws, size_t ws_size,
                              hipStream_t stream) {
  const float* x    = (const float*)d_in[0];
  const int*   ei   = (const int*)d_in[1];
  const float* l1w  = (const float*)d_in[2];
  const float* l1as = (const float*)d_in[3];
  const float* l1ad = (const float*)d_in[4];
  const float* l1ha = (const float*)d_in[5];
  const float* l1b  = (const float*)d_in[6];
  const float* l2w  = (const float*)d_in[7];
  const float* l2as = (const float*)d_in[8];
  const float* l2ad = (const float*)d_in[9];
  const float* l2ha = (const float*)d_in[10];
  const float* l2rw = (const float*)d_in[11];
  const float* lns  = (const float*)d_in[12];
  const float* lnb  = (const float*)d_in[13];
  const float* l2b  = (const float*)d_in[14];
  int E = in_sizes[1] / 2;

  // ---- workspace layout (bytes) ----
  size_t o = 0;
  auto take = [&](size_t bytes) { size_t r = o; o += (bytes + 255) & ~(size_t)255; return r; };
  size_t oRB  = take((size_t)kN * kWords * 8);      // rowbits
  size_t oCB  = take((size_t)kWords * kN * 8);      // colbitsT
  size_t oCB2 = take((size_t)kWords * kN * 8);      // colbits2T (A2 structure)
  size_t zEnd = o;                                  // zero region end
  size_t oMF  = take((size_t)kN * kN * 4);
  size_t oHX1 = take((size_t)2 * kN * kC1 * 4);
  size_t oH   = take((size_t)kN * kC1 * 4);
  size_t oHX2 = take((size_t)3 * kN * kC2 * 4);     // hop0 | hop1 | res
  size_t oSS1 = take((size_t)2 * kN * 4 * 4);
  size_t oSD1 = take((size_t)2 * kN * 4 * 4);
  size_t oSS2 = take((size_t)2 * kN * 4);
  size_t oSD2 = take((size_t)2 * kN * 4);
  size_t oST1 = take((size_t)2 * kN * 4 * 4 * 4);
  size_t oST2 = take((size_t)2 * kN * 4 * 4);
  if (ws_size < o) return;  // insufficient scratch; fail visibly

  char* w = (char*)d_ws;
  unsigned long long* rowbits = (unsigned long long*)(w + oRB);
  unsigned long long* colbitsT = (unsigned long long*)(w + oCB);
  unsigned long long* colbits2T = (unsigned long long*)(w + oCB2);
  float* motif = (float*)(w + oMF);
  float* hx1 = (float*)(w + oHX1);
  float* hbuf = (float*)(w + oH);
  float* hx2 = (float*)(w + oHX2);
  float* res = hx2 + (size_t)2 * kN * kC2;
  float* ss1 = (float*)(w + oSS1);
  float* sd1 = (float*)(w + oSD1);
  float* ss2 = (float*)(w + oSS2);
  float* sd2 = (float*)(w + oSD2);
  float* st1 = (float*)(w + oST1);
  float* st2 = (float*)(w + oST2);

  hipMemsetAsync(d_ws, 0, zEnd, stream);

  build_bits<<<(E + 255) / 256, 256, 0, stream>>>(ei, E, rowbits, colbitsT);
  a3_motif<<<kN, 256, 0, stream>>>(rowbits, motif, colbits2T);

  // ---- layer 1 (H=4, C=64, concat) ----
  gemm_batched<<<dim3(kC1 / 64, kN / 64, 2), 256, 0, stream>>>(
      x, l1w, l1w, hx1, kN, kC1, kIN, 2);
  src_dst<4><<<dim3(kN, 2), 256, 0, stream>>>(hx1, l1as, l1ad, ss1, sd1);
  stats_bits<4><<<dim3(kN / 4, 2), 256, 0, stream>>>(
      ss1, sd1, motif, colbitsT, colbits2T, st1);
  agg_l1<<<kN, 256, 0, stream>>>(hx1, ss1, sd1, motif, colbitsT, colbits2T,
                                 st1, l1ha, l1b, hbuf);

  // ---- layer 2 (H=1, C=64, residual + LN) ----
  gemm_batched<<<dim3(1, kN / 64, 3), 256, 0, stream>>>(
      hbuf, l2w, l2rw, hx2, kN, kC2, kC1, 2);
  src_dst<1><<<dim3(kN, 2), 64, 0, stream>>>(hx2, l2as, l2ad, ss2, sd2);
  stats_bits<1><<<dim3(kN / 4, 2), 256, 0, stream>>>(
      ss2, sd2, motif, colbitsT, colbits2T, st2);
  agg_l2<<<kN, 256, 0, stream>>>(hx2, ss2, sd2, motif, colbitsT, colbits2T,
                                 st2, l2ha, res, lns, lnb, l2b, (float*)d_out);
}

// Round 9
// 230.380 us; speedup vs baseline: 1.0514x; 1.0172x over previous
//
#include <hip/hip_runtime.h>

namespace {

constexpr int kN = 2048;
constexpr int kWords = kN / 64;   // 32
constexpr int kC1 = 256;          // HEADS*HID
constexpr int kC2 = 64;           // OUT_CH
constexpr int kIN = 512;
constexpr float kNegSlope = 0.2f;
constexpr float kLnEps = 1e-5f;

__device__ __forceinline__ float leakyf(float v) {
  return v >= 0.f ? v : kNegSlope * v;
}
// online softmax accumulate (masked stream)
__device__ __forceinline__ void onl(float& m, float& l, float v) {
  if (v > m) { l = l * __expf(m - v) + 1.f; m = v; }
  else       { l += __expf(v - m); }
}
__device__ __forceinline__ void mergeml(float& M, float& L, float m, float l) {
  if (m > M) { L = L * __expf(M - m) + l; M = m; }
  else       { L += l * __expf(m - M); }
}

// ---------------- adjacency bitsets ----------------
__global__ void build_bits(const int* __restrict__ ei, int E,
                           unsigned long long* rowbits, unsigned long long* colbitsT) {
  int e = blockIdx.x * 256 + threadIdx.x;
  if (e >= E) return;
  int s = ei[e], d = ei[E + e];
  atomicOr(&rowbits[(size_t)s * kWords + (d >> 6)], 1ull << (d & 63));
  atomicOr(&colbitsT[(size_t)(s >> 6) * kN + d], 1ull << (s & 63));
}

// fat1: blocks [0,kN) = fused A2/A3/motif row; blocks [kN, kN+256) = layer-1
// GEMM tiles (2 hops x 32 row-tiles x 4 col-tiles) with fused s_src/s_dst
// epilogue (each 64-col tile == one head; no atomics needed).
__global__ __launch_bounds__(256) void fat1(
    const unsigned long long* __restrict__ rowbits,
    float* __restrict__ motif,
    unsigned long long* __restrict__ colbits2T,
    const float* __restrict__ x,
    const float* __restrict__ l1w,
    float* __restrict__ hx1,
    const float* __restrict__ l1as,
    const float* __restrict__ l1ad,
    float* __restrict__ ss1, float* __restrict__ sd1) {
  __shared__ __align__(16) char smem[12416];
  int t = threadIdx.x;
  if (blockIdx.x < kN) {
    // ---------------- a3_motif row ----------------
    int s = blockIdx.x;
    int lane = t & 63;
    unsigned int* cntp = (unsigned int*)smem;            // 4 KB packed u16 A2
    unsigned int* sumsp = (unsigned int*)(smem + 4096);  // 4 KB packed u16 A3
    unsigned short* list = (unsigned short*)(smem + 8192); // 4 KB
    int* n_total = (int*)(smem + 12288);
    float* redv = (float*)(smem + 12304);
    reinterpret_cast<uint4*>(cntp)[t] = make_uint4(0u, 0u, 0u, 0u);
    reinterpret_cast<uint4*>(sumsp)[t] = make_uint4(0u, 0u, 0u, 0u);
    __syncthreads();
    if (t < 64) {
      unsigned long long word = (lane < kWords) ? rowbits[(size_t)s * kWords + lane] : 0ull;
      int c = __popcll(word);
      int inc = c;
      for (int o = 1; o < 64; o <<= 1) { int v = __shfl_up(inc, o); if (lane >= o) inc += v; }
      if (lane == 63) *n_total = inc;
      int off = inc - c;
      int base = lane * 64;
      while (word) {
        int b = __builtin_ctzll(word);
        word &= word - 1;
        list[off++] = (unsigned short)(base + b);
      }
    }
    __syncthreads();
    int jtot = *n_total;
    int wsel = t & 31;
    int baseh = wsel << 5;
    int tot1 = jtot * kWords;
    for (int idx = t; idx < tot1; idx += 512) {
      unsigned long long w1 = rowbits[(size_t)list[idx >> 5] * kWords + wsel];
      unsigned long long w2 = 0;
      if (idx + 256 < tot1)
        w2 = rowbits[(size_t)list[(idx + 256) >> 5] * kWords + wsel];
      while (w1) {
        int b = __builtin_ctzll(w1); w1 &= w1 - 1;
        atomicAdd(&cntp[baseh + (b >> 1)], 1u << ((b & 1) * 16));
      }
      while (w2) {
        int b = __builtin_ctzll(w2); w2 &= w2 - 1;
        atomicAdd(&cntp[baseh + (b >> 1)], 1u << ((b & 1) * 16));
      }
    }
    __syncthreads();
    if (t < 64) {
      int kb = lane * 32;
      unsigned int m = 0;
#pragma unroll
      for (int i2 = 0; i2 < 16; ++i2) {
        unsigned int pw = cntp[(kb >> 1) + i2];
        if (pw & 0xffffu) m |= 1u << (2 * i2);
        if (pw >> 16)     m |= 1u << (2 * i2 + 1);
      }
      int c = __popc(m);
      int inc = c;
      for (int o = 1; o < 64; o <<= 1) { int v = __shfl_up(inc, o); if (lane >= o) inc += v; }
      if (lane == 63) *n_total = inc;
      int off = inc - c;
      while (m) {
        int b = __builtin_ctz(m);
        m &= m - 1;
        int k = kb + b;
        list[off++] = (unsigned short)k;
        atomicOr(&colbits2T[(size_t)(s >> 6) * kN + k], 1ull << (s & 63));
      }
    }
    __syncthreads();
    int ktot = *n_total;
    int tot3 = ktot * kWords;
    for (int idx = t; idx < tot3; idx += 1024) {
      unsigned long long wd[4];
      int kk[4];
#pragma unroll
      for (int u = 0; u < 4; ++u) {
        int id = idx + u * 256;
        if (id < tot3) {
          kk[u] = list[id >> 5];
          wd[u] = rowbits[(size_t)kk[u] * kWords + wsel];
        } else { kk[u] = 0; wd[u] = 0ull; }
      }
#pragma unroll
      for (int u = 0; u < 4; ++u) {
        unsigned long long word = wd[u];
        if (!word) continue;
        unsigned int cp = cntp[kk[u] >> 1];
        unsigned int ck = (cp >> ((kk[u] & 1) * 16)) & 0xffffu;
        while (word) {
          int b = __builtin_ctzll(word); word &= word - 1;
          atomicAdd(&sumsp[baseh + (b >> 1)], ck << ((b & 1) * 16));
        }
      }
    }
    __syncthreads();
    float tot = 0.f;
    float sv[8];
#pragma unroll
    for (int c = 0; c < 8; ++c) {
      int d = t + c * 256;
      sv[c] = (float)((sumsp[d >> 1] >> ((d & 1) * 16)) & 0xffffu);
      tot += sv[c];
    }
    for (int o = 32; o; o >>= 1) tot += __shfl_xor(tot, o);
    if (lane == 0) redv[t >> 6] = tot;
    __syncthreads();
    float inv = 1.f / fmaxf(redv[0] + redv[1] + redv[2] + redv[3], 1.f);
#pragma unroll
    for (int c = 0; c < 8; ++c)
      motif[(size_t)s * kN + t + c * 256] = sv[c] * inv;
  } else {
    // ---------------- layer-1 GEMM tile + src/dst epilogue ----------------
    int idx = blockIdx.x - kN;       // [0, 256)
    int hop = idx >> 7;
    int rem = idx & 127;
    int row0 = (rem >> 2) * 64, col0 = (rem & 3) * 64;
    const float* B = l1w + (size_t)hop * kIN * kC1;
    float* Cz = hx1 + (size_t)hop * kN * kC1;
    float (*As)[65] = (float(*)[65])smem;
    float (*Bs)[65] = (float(*)[65])(smem + 4160);
    int tx = t & 15, ty = t >> 4;
    float acc[4][4] = {};
    for (int k0 = 0; k0 < kIN; k0 += 16) {
      {
        int e = t * 4;
        int m = e >> 4, kk = e & 15;
        float4 va = *reinterpret_cast<const float4*>(x + (size_t)(row0 + m) * kIN + k0 + kk);
        As[kk + 0][m] = va.x; As[kk + 1][m] = va.y;
        As[kk + 2][m] = va.z; As[kk + 3][m] = va.w;
      }
      {
        int kb = t >> 4, nb = (t & 15) * 4;
        float4 vb = *reinterpret_cast<const float4*>(B + (size_t)(k0 + kb) * kC1 + col0 + nb);
        Bs[kb][nb + 0] = vb.x; Bs[kb][nb + 1] = vb.y;
        Bs[kb][nb + 2] = vb.z; Bs[kb][nb + 3] = vb.w;
      }
      __syncthreads();
#pragma unroll
      for (int kk2 = 0; kk2 < 16; ++kk2) {
        float a[4], b[4];
#pragma unroll
        for (int i = 0; i < 4; ++i) a[i] = As[kk2][ty * 4 + i];
#pragma unroll
        for (int j = 0; j < 4; ++j) b[j] = Bs[kk2][tx * 4 + j];
#pragma unroll
        for (int i = 0; i < 4; ++i)
#pragma unroll
          for (int j = 0; j < 4; ++j) acc[i][j] += a[i] * b[j];
      }
      __syncthreads();
    }
#pragma unroll
    for (int i = 0; i < 4; ++i)
#pragma unroll
      for (int j = 0; j < 4; ++j)
        Cz[(size_t)(row0 + ty * 4 + i) * kC1 + col0 + tx * 4 + j] = acc[i][j];
    // epilogue: s_src/s_dst for this head (col tile) and these 64 rows
    int h = col0 >> 6;
    float as_[4], ad_[4];
#pragma unroll
    for (int j = 0; j < 4; ++j) {
      as_[j] = l1as[hop * kC1 + col0 + tx * 4 + j];
      ad_[j] = l1ad[hop * kC1 + col0 + tx * 4 + j];
    }
#pragma unroll
    for (int i = 0; i < 4; ++i) {
      float ps = acc[i][0] * as_[0] + acc[i][1] * as_[1] +
                 acc[i][2] * as_[2] + acc[i][3] * as_[3];
      float pd = acc[i][0] * ad_[0] + acc[i][1] * ad_[1] +
                 acc[i][2] * ad_[2] + acc[i][3] * ad_[3];
#pragma unroll
      for (int o = 1; o < 16; o <<= 1) {
        ps += __shfl_xor(ps, o);
        pd += __shfl_xor(pd, o);
      }
      if (tx == 0) {
        int n = row0 + ty * 4 + i;
        ss1[((size_t)hop * kN + n) * 4 + h] = ps;
        sd1[((size_t)hop * kN + n) * 4 + h] = pd;
      }
    }
  }
}

// layer-2 GEMM (z: 0,1 = hops via l2w with src/dst epilogue; 2 = res via l2rw)
__global__ __launch_bounds__(256) void gemm2(
    const float* __restrict__ A, const float* __restrict__ l2w,
    const float* __restrict__ l2rw, float* __restrict__ C,
    const float* __restrict__ attS, const float* __restrict__ attD,
    float* __restrict__ ssO, float* __restrict__ sdO) {
  int z = blockIdx.z;
  const float* B = (z < 2) ? l2w + (size_t)z * kC1 * kC2 : l2rw;
  float* Cz = C + (size_t)z * kN * kC2;
  __shared__ float As[16][65];
  __shared__ float Bs[16][65];
  int t = threadIdx.x;
  int tx = t & 15, ty = t >> 4;
  int row0 = blockIdx.y * 64;
  float acc[4][4] = {};
  for (int k0 = 0; k0 < kC1; k0 += 16) {
    {
      int e = t * 4;
      int m = e >> 4, kk = e & 15;
      float4 va = *reinterpret_cast<const float4*>(A + (size_t)(row0 + m) * kC1 + k0 + kk);
      As[kk + 0][m] = va.x; As[kk + 1][m] = va.y;
      As[kk + 2][m] = va.z; As[kk + 3][m] = va.w;
    }
    {
      int kb = t >> 4, nb = (t & 15) * 4;
      float4 vb = *reinterpret_cast<const float4*>(B + (size_t)(k0 + kb) * kC2 + nb);
      Bs[kb][nb + 0] = vb.x; Bs[kb][nb + 1] = vb.y;
      Bs[kb][nb + 2] = vb.z; Bs[kb][nb + 3] = vb.w;
    }
    __syncthreads();
#pragma unroll
    for (int kk2 = 0; kk2 < 16; ++kk2) {
      float a[4], b[4];
#pragma unroll
      for (int i = 0; i < 4; ++i) a[i] = As[kk2][ty * 4 + i];
#pragma unroll
      for (int j = 0; j < 4; ++j) b[j] = Bs[kk2][tx * 4 + j];
#pragma unroll
      for (int i = 0; i < 4; ++i)
#pragma unroll
        for (int j = 0; j < 4; ++j) acc[i][j] += a[i] * b[j];
    }
    __syncthreads();
  }
#pragma unroll
  for (int i = 0; i < 4; ++i)
#pragma unroll
    for (int j = 0; j < 4; ++j)
      Cz[(size_t)(row0 + ty * 4 + i) * kC2 + tx * 4 + j] = acc[i][j];
  if (z < 2) {
    float as_[4], ad_[4];
#pragma unroll
    for (int j = 0; j < 4; ++j) {
      as_[j] = attS[z * kC2 + tx * 4 + j];
      ad_[j] = attD[z * kC2 + tx * 4 + j];
    }
#pragma unroll
    for (int i = 0; i < 4; ++i) {
      float ps = acc[i][0] * as_[0] + acc[i][1] * as_[1] +
                 acc[i][2] * as_[2] + acc[i][3] * as_[3];
      float pd = acc[i][0] * ad_[0] + acc[i][1] * ad_[1] +
                 acc[i][2] * ad_[2] + acc[i][3] * ad_[3];
#pragma unroll
      for (int o = 1; o < 16; o <<= 1) {
        ps += __shfl_xor(ps, o);
        pd += __shfl_xor(pd, o);
      }
      if (tx == 0) {
        int n = row0 + ty * 4 + i;
        ssO[(size_t)z * kN + n] = ps;
        sdO[(size_t)z * kN + n] = pd;
      }
    }
  }
}

// layer-1 aggregation with fused stats: one dst per block (256 thr = 256
// channels = 4 head-waves), both hops, sparse s-list; bias + ELU. grid = N.
__global__ __launch_bounds__(256) void agg_l1(
    const float* __restrict__ hx,      // [2][N][256]
    const float* __restrict__ ssrc,    // [2][N][4]
    const float* __restrict__ sdst,    // [2][N][4]
    const float* __restrict__ motif,
    const unsigned long long* __restrict__ colbitsT,
    const unsigned long long* __restrict__ colbits2T,
    const float* __restrict__ hop_att,
    const float* __restrict__ bias,
    float* __restrict__ hbuf) {
  int d = blockIdx.x;
  int t = threadIdx.x;
  int lane = t & 63;
  int h = t >> 6;
  __shared__ unsigned short slist[kN];
  __shared__ float w_lds[64 * 4];
  __shared__ int s_total;
  float a0 = hop_att[0], a1 = hop_att[1];
  float mxa = fmaxf(a0, a1);
  float e0 = __expf(a0 - mxa), e1 = __expf(a1 - mxa);
  float wh0 = e0 / (e0 + e1), wh1 = e1 / (e0 + e1);
  float acc = 0.f;
  for (int hop = 0; hop < 2; ++hop) {
    const unsigned long long* cm = hop ? colbits2T : colbitsT;
    if (t < 64) {
      unsigned long long word = (lane < kWords) ? cm[(size_t)lane * kN + d] : 0ull;
      if (lane == (d >> 6)) word |= 1ull << (d & 63);
      int cnt = __popcll(word);
      int inc = cnt;
      for (int o = 1; o < 64; o <<= 1) { int v = __shfl_up(inc, o); if (lane >= o) inc += v; }
      if (lane == 63) s_total = inc;
      int off = inc - cnt;
      int base = lane * 64;
      while (word) {
        int b = __builtin_ctzll(word);
        word &= word - 1;
        slist[off++] = (unsigned short)(base + b);
      }
    }
    __syncthreads();
    int total = s_total;
    float sd = sdst[((size_t)hop * kN + d) * 4 + h];
    const float* hxp = hx + (size_t)hop * kN * kC1;
    const float* ssp = ssrc + (size_t)hop * kN * 4;
    // fused stats: wave h computes online-softmax stats for head h
    float m1 = -3.0e38f, l1v = 0.f, m2 = -3.0e38f, l2v = 0.f;
    for (int q = lane; q < total; q += 64) {
      int s = slist[q];
      float mv = motif[(size_t)s * kN + d];
      float v = ssp[s * 4 + h] + sd;
      onl(m1, l1v, leakyf(v));
      onl(m2, l2v, leakyf(v * mv));
    }
#pragma unroll
    for (int o = 1; o < 64; o <<= 1) {
      float mm = __shfl_xor(m1, o), ll = __shfl_xor(l1v, o);
      mergeml(m1, l1v, mm, ll);
      float mm2 = __shfl_xor(m2, o), ll2 = __shfl_xor(l2v, o);
      mergeml(m2, l2v, mm2, ll2);
    }
    float il1 = 1.f / l1v, il2 = 1.f / l2v;
    float wh = hop ? wh1 : wh0;
    for (int c0 = 0; c0 < total; c0 += 64) {
      int nsi = min(64, total - c0);
      if (lane < nsi) {
        int s = slist[c0 + lane];
        float mv = motif[(size_t)s * kN + d];
        float v = ssp[s * 4 + h] + sd;
        w_lds[lane * 4 + h] = (0.5f * __expf(leakyf(v) - m1) * il1 +
                               0.5f * __expf(leakyf(v * mv) - m2) * il2) * wh;
      }
      __syncthreads();
      int q = 0;
      for (; q + 4 <= nsi; q += 4) {
        int s0 = slist[c0 + q + 0], s1 = slist[c0 + q + 1];
        int s2 = slist[c0 + q + 2], s3 = slist[c0 + q + 3];
        float r0 = hxp[(size_t)s0 * kC1 + t];
        float r1 = hxp[(size_t)s1 * kC1 + t];
        float r2 = hxp[(size_t)s2 * kC1 + t];
        float r3 = hxp[(size_t)s3 * kC1 + t];
        acc += w_lds[(q + 0) * 4 + h] * r0 + w_lds[(q + 1) * 4 + h] * r1 +
               w_lds[(q + 2) * 4 + h] * r2 + w_lds[(q + 3) * 4 + h] * r3;
      }
      for (; q < nsi; ++q) {
        int s = slist[c0 + q];
        acc += w_lds[q * 4 + h] * hxp[(size_t)s * kC1 + t];
      }
      __syncthreads();
    }
    __syncthreads();
  }
  acc += bias[t];
  hbuf[(size_t)d * kC1 + t] = acc > 0.f ? acc : __expf(acc) - 1.f;
}

// layer-2 aggregation with fused stats: one dst per block, 4 si-subgroups x
// 64 channels; fused residual + LayerNorm + bias -> output. grid = N.
__global__ __launch_bounds__(256) void agg_l2(
    const float* __restrict__ hx,      // [2][N][64]
    const float* __restrict__ ssrc,    // [2][N]
    const float* __restrict__ sdst,    // [2][N]
    const float* __restrict__ motif,
    const unsigned long long* __restrict__ colbitsT,
    const unsigned long long* __restrict__ colbits2T,
    const float* __restrict__ hop_att,
    const float* __restrict__ res,     // [N][64]
    const float* __restrict__ lns, const float* __restrict__ lnb,
    const float* __restrict__ l2b,
    float* __restrict__ out) {
  int d = blockIdx.x;
  int t = threadIdx.x;
  int lane = t & 63;   // channel
  int g = t >> 6;      // si-subgroup / wave
  __shared__ unsigned short slist[kN];
  __shared__ float w_lds[64];
  __shared__ int s_total;
  __shared__ float red[4][64];
  __shared__ float smst[4][4];
  float a0 = hop_att[0], a1 = hop_att[1];
  float mxa = fmaxf(a0, a1);
  float e0 = __expf(a0 - mxa), e1 = __expf(a1 - mxa);
  float wh0 = e0 / (e0 + e1), wh1 = e1 / (e0 + e1);
  float acc = 0.f;
  for (int hop = 0; hop < 2; ++hop) {
    const unsigned long long* cm = hop ? colbits2T : colbitsT;
    if (t < 64) {
      unsigned long long word = (lane < kWords) ? cm[(size_t)lane * kN + d] : 0ull;
      if (lane == (d >> 6)) word |= 1ull << (d & 63);
      int cnt = __popcll(word);
      int inc = cnt;
      for (int o = 1; o < 64; o <<= 1) { int v = __shfl_up(inc, o); if (lane >= o) inc += v; }
      if (lane == 63) s_total = inc;
      int off = inc - cnt;
      int base = lane * 64;
      while (word) {
        int b = __builtin_ctzll(word);
        word &= word - 1;
        slist[off++] = (unsigned short)(base + b);
      }
    }
    __syncthreads();
    int total = s_total;
    float sd = sdst[(size_t)hop * kN + d];
    const float* hxp = hx + (size_t)hop * kN * kC2;
    const float* ssp = ssrc + (size_t)hop * kN;
    // fused stats: all 256 threads, then wave butterfly + cross-wave merge
    float m1 = -3.0e38f, l1v = 0.f, m2 = -3.0e38f, l2v = 0.f;
    for (int q = t; q < total; q += 256) {
      int s = slist[q];
      float mv = motif[(size_t)s * kN + d];
      float v = ssp[s] + sd;
      onl(m1, l1v, leakyf(v));
      onl(m2, l2v, leakyf(v * mv));
    }
#pragma unroll
    for (int o = 1; o < 64; o <<= 1) {
      float mm = __shfl_xor(m1, o), ll = __shfl_xor(l1v, o);
      mergeml(m1, l1v, mm, ll);
      float mm2 = __shfl_xor(m2, o), ll2 = __shfl_xor(l2v, o);
      mergeml(m2, l2v, mm2, ll2);
    }
    if (lane == 0) {
      smst[g][0] = m1; smst[g][1] = l1v; smst[g][2] = m2; smst[g][3] = l2v;
    }
    __syncthreads();
    float M1 = -3.0e38f, L1 = 0.f, M2 = -3.0e38f, L2 = 0.f;
#pragma unroll
    for (int gg = 0; gg < 4; ++gg) {
      mergeml(M1, L1, smst[gg][0], smst[gg][1]);
      mergeml(M2, L2, smst[gg][2], smst[gg][3]);
    }
    float il1 = 1.f / L1, il2 = 1.f / L2;
    float wh = hop ? wh1 : wh0;
    for (int c0 = 0; c0 < total; c0 += 64) {
      int nsi = min(64, total - c0);
      if (t < nsi) {
        int s = slist[c0 + t];
        float mv = motif[(size_t)s * kN + d];
        float v = ssp[s] + sd;
        w_lds[t] = (0.5f * __expf(leakyf(v) - M1) * il1 +
                    0.5f * __expf(leakyf(v * mv) - M2) * il2) * wh;
      }
      __syncthreads();
      int q = g;
      for (; q + 4 < nsi; q += 8) {
        int s0 = slist[c0 + q], s1 = slist[c0 + q + 4];
        float r0 = hxp[(size_t)s0 * kC2 + lane];
        float r1 = hxp[(size_t)s1 * kC2 + lane];
        acc += w_lds[q] * r0 + w_lds[q + 4] * r1;
      }
      if (q < nsi) {
        int s0 = slist[c0 + q];
        acc += w_lds[q] * hxp[(size_t)s0 * kC2 + lane];
      }
      __syncthreads();
    }
    __syncthreads();
  }
  red[g][lane] = acc;
  __syncthreads();
  if (t < 64) {
    float v = red[0][t] + red[1][t] + red[2][t] + red[3][t] + res[(size_t)d * kC2 + t];
    float s = v;
    for (int o = 32; o; o >>= 1) s += __shfl_xor(s, o);
    float mu = s * (1.f / kC2);
    float dv = v - mu;
    float q = dv * dv;
    for (int o = 32; o; o >>= 1) q += __shfl_xor(q, o);
    float var = q * (1.f / kC2);
    out[(size_t)d * kC2 + t] = dv * rsqrtf(var + kLnEps) * lns[t] + lnb[t] + l2b[t];
  }
}

}  // namespace

extern "C" void kernel_launch(void* const* d_in, const int* in_sizes, int n_in,
                              void* d_out, int out_size, void* d_ws, size_t ws_size,
                              hipStream_t stream) {
  const float* x    = (const float*)d_in[0];
  const int*   ei   = (const int*)d_in[1];
  const float* l1w  = (const float*)d_in[2];
  const float* l1as = (const float*)d_in[3];
  const float* l1ad = (const float*)d_in[4];
  const float* l1ha = (const float*)d_in[5];
  const float* l1b  = (const float*)d_in[6];
  const float* l2w  = (const float*)d_in[7];
  const float* l2as = (const float*)d_in[8];
  const float* l2ad = (const float*)d_in[9];
  const float* l2ha = (const float*)d_in[10];
  const float* l2rw = (const float*)d_in[11];
  const float* lns  = (const float*)d_in[12];
  const float* lnb  = (const float*)d_in[13];
  const float* l2b  = (const float*)d_in[14];
  int E = in_sizes[1] / 2;

  // ---- workspace layout (bytes) ----
  size_t o = 0;
  auto take = [&](size_t bytes) { size_t r = o; o += (bytes + 255) & ~(size_t)255; return r; };
  size_t oRB  = take((size_t)kN * kWords * 8);      // rowbits
  size_t oCB  = take((size_t)kWords * kN * 8);      // colbitsT
  size_t oCB2 = take((size_t)kWords * kN * 8);      // colbits2T (A2 structure)
  size_t zEnd = o;                                  // zero region end
  size_t oMF  = take((size_t)kN * kN * 4);
  size_t oHX1 = take((size_t)2 * kN * kC1 * 4);
  size_t oH   = take((size_t)kN * kC1 * 4);
  size_t oHX2 = take((size_t)3 * kN * kC2 * 4);     // hop0 | hop1 | res
  size_t oSS1 = take((size_t)2 * kN * 4 * 4);
  size_t oSD1 = take((size_t)2 * kN * 4 * 4);
  size_t oSS2 = take((size_t)2 * kN * 4);
  size_t oSD2 = take((size_t)2 * kN * 4);
  if (ws_size < o) return;  // insufficient scratch; fail visibly

  char* w = (char*)d_ws;
  unsigned long long* rowbits = (unsigned long long*)(w + oRB);
  unsigned long long* colbitsT = (unsigned long long*)(w + oCB);
  unsigned long long* colbits2T = (unsigned long long*)(w + oCB2);
  float* motif = (float*)(w + oMF);
  float* hx1 = (float*)(w + oHX1);
  float* hbuf = (float*)(w + oH);
  float* hx2 = (float*)(w + oHX2);
  float* res = hx2 + (size_t)2 * kN * kC2;
  float* ss1 = (float*)(w + oSS1);
  float* sd1 = (float*)(w + oSD1);
  float* ss2 = (float*)(w + oSS2);
  float* sd2 = (float*)(w + oSD2);

  hipMemsetAsync(d_ws, 0, zEnd, stream);

  build_bits<<<(E + 255) / 256, 256, 0, stream>>>(ei, E, rowbits, colbitsT);

  // motif/A2-structure rows co-scheduled with layer-1 GEMM (+src/dst epilogue)
  fat1<<<kN + 256, 256, 0, stream>>>(rowbits, motif, colbits2T,
                                     x, l1w, hx1, l1as, l1ad, ss1, sd1);

  agg_l1<<<kN, 256, 0, stream>>>(hx1, ss1, sd1, motif, colbitsT, colbits2T,
                                 l1ha, l1b, hbuf);

  gemm2<<<dim3(1, kN / 64, 3), 256, 0, stream>>>(hbuf, l2w, l2rw, hx2,
                                                 l2as, l2ad, ss2, sd2);

  agg_l2<<<kN, 256, 0, stream>>>(hx2, ss2, sd2, motif, colbitsT, colbits2T,
                                 l2ha, res, lns, lnb, l2b, (float*)d_out);
}

// Round 10
// 209.146 us; speedup vs baseline: 1.1581x; 1.1015x over previous
//
#include <hip/hip_runtime.h>

namespace {

constexpr int kN = 2048;
constexpr int kWords = kN / 64;   // 32
constexpr int kC1 = 256;          // HEADS*HID
constexpr int kC2 = 64;           // OUT_CH
constexpr int kIN = 512;
constexpr float kNegSlope = 0.2f;
constexpr float kLnEps = 1e-5f;

__device__ __forceinline__ float leakyf(float v) {
  return v >= 0.f ? v : kNegSlope * v;
}
__device__ __forceinline__ void onl(float& m, float& l, float v) {
  if (v > m) { l = l * __expf(m - v) + 1.f; m = v; }
  else       { l += __expf(v - m); }
}
__device__ __forceinline__ void mergeml(float& M, float& L, float m, float l) {
  if (m > M) { L = L * __expf(M - m) + l; M = m; }
  else       { L += l * __expf(m - M); }
}

// ---------------- adjacency bitsets ----------------
__global__ void build_bits(const int* __restrict__ ei, int E,
                           unsigned long long* rowbits, unsigned long long* colbitsT) {
  int e = blockIdx.x * 256 + threadIdx.x;
  if (e >= E) return;
  int s = ei[e], d = ei[E + e];
  atomicOr(&rowbits[(size_t)s * kWords + (d >> 6)], 1ull << (d & 63));
  atomicOr(&colbitsT[(size_t)(s >> 6) * kN + d], 1ull << (s & 63));
}

// fat1: interleaved block types — every 9th block is a layer-1 GEMM tile
// (with fused s_src/s_dst epilogue), the rest are fused A2/A3/motif rows.
// Interleaving makes both types co-resident from t=0 (latency-bound motif
// overlaps compute-bound GEMM).
__global__ __launch_bounds__(256) void fat1(
    const unsigned long long* __restrict__ rowbits,
    float* __restrict__ motif,
    unsigned long long* __restrict__ colbits2T,
    const float* __restrict__ x,
    const float* __restrict__ l1w,
    float* __restrict__ hx1,
    const float* __restrict__ l1as,
    const float* __restrict__ l1ad,
    float* __restrict__ ss1, float* __restrict__ sd1) {
  __shared__ __align__(16) char smem[12416];
  int t = threadIdx.x;
  int bid = blockIdx.x;
  int r9 = bid % 9, g9 = bid / 9;
  if (r9 != 8) {
    // ---------------- a3_motif row ----------------
    int s = g9 * 8 + r9;
    int lane = t & 63;
    unsigned int* cntp = (unsigned int*)smem;            // 4 KB packed u16 A2
    unsigned int* sumsp = (unsigned int*)(smem + 4096);  // 4 KB packed u16 A3
    unsigned short* list = (unsigned short*)(smem + 8192); // 4 KB
    int* n_total = (int*)(smem + 12288);
    float* redv = (float*)(smem + 12304);
    reinterpret_cast<uint4*>(cntp)[t] = make_uint4(0u, 0u, 0u, 0u);
    reinterpret_cast<uint4*>(sumsp)[t] = make_uint4(0u, 0u, 0u, 0u);
    __syncthreads();
    if (t < 64) {
      unsigned long long word = (lane < kWords) ? rowbits[(size_t)s * kWords + lane] : 0ull;
      int c = __popcll(word);
      int inc = c;
      for (int o = 1; o < 64; o <<= 1) { int v = __shfl_up(inc, o); if (lane >= o) inc += v; }
      if (lane == 63) *n_total = inc;
      int off = inc - c;
      int base = lane * 64;
      while (word) {
        int b = __builtin_ctzll(word);
        word &= word - 1;
        list[off++] = (unsigned short)(base + b);
      }
    }
    __syncthreads();
    int jtot = *n_total;
    int wsel = t & 31;
    int baseh = wsel << 5;
    int tot1 = jtot * kWords;
    for (int idx = t; idx < tot1; idx += 512) {
      unsigned long long w1 = rowbits[(size_t)list[idx >> 5] * kWords + wsel];
      unsigned long long w2 = 0;
      if (idx + 256 < tot1)
        w2 = rowbits[(size_t)list[(idx + 256) >> 5] * kWords + wsel];
      while (w1) {
        int b = __builtin_ctzll(w1); w1 &= w1 - 1;
        atomicAdd(&cntp[baseh + (b >> 1)], 1u << ((b & 1) * 16));
      }
      while (w2) {
        int b = __builtin_ctzll(w2); w2 &= w2 - 1;
        atomicAdd(&cntp[baseh + (b >> 1)], 1u << ((b & 1) * 16));
      }
    }
    __syncthreads();
    if (t < 64) {
      int kb = lane * 32;
      unsigned int m = 0;
#pragma unroll
      for (int i2 = 0; i2 < 16; ++i2) {
        unsigned int pw = cntp[(kb >> 1) + i2];
        if (pw & 0xffffu) m |= 1u << (2 * i2);
        if (pw >> 16)     m |= 1u << (2 * i2 + 1);
      }
      int c = __popc(m);
      int inc = c;
      for (int o = 1; o < 64; o <<= 1) { int v = __shfl_up(inc, o); if (lane >= o) inc += v; }
      if (lane == 63) *n_total = inc;
      int off = inc - c;
      while (m) {
        int b = __builtin_ctz(m);
        m &= m - 1;
        int k = kb + b;
        list[off++] = (unsigned short)k;
        atomicOr(&colbits2T[(size_t)(s >> 6) * kN + k], 1ull << (s & 63));
      }
    }
    __syncthreads();
    int ktot = *n_total;
    int tot3 = ktot * kWords;
    for (int idx = t; idx < tot3; idx += 1024) {
      unsigned long long wd[4];
      int kk[4];
#pragma unroll
      for (int u = 0; u < 4; ++u) {
        int id = idx + u * 256;
        if (id < tot3) {
          kk[u] = list[id >> 5];
          wd[u] = rowbits[(size_t)kk[u] * kWords + wsel];
        } else { kk[u] = 0; wd[u] = 0ull; }
      }
#pragma unroll
      for (int u = 0; u < 4; ++u) {
        unsigned long long word = wd[u];
        if (!word) continue;
        unsigned int cp = cntp[kk[u] >> 1];
        unsigned int ck = (cp >> ((kk[u] & 1) * 16)) & 0xffffu;
        while (word) {
          int b = __builtin_ctzll(word); word &= word - 1;
          atomicAdd(&sumsp[baseh + (b >> 1)], ck << ((b & 1) * 16));
        }
      }
    }
    __syncthreads();
    float tot = 0.f;
    float sv[8];
#pragma unroll
    for (int c = 0; c < 8; ++c) {
      int d = t + c * 256;
      sv[c] = (float)((sumsp[d >> 1] >> ((d & 1) * 16)) & 0xffffu);
      tot += sv[c];
    }
    for (int o = 32; o; o >>= 1) tot += __shfl_xor(tot, o);
    if (lane == 0) redv[t >> 6] = tot;
    __syncthreads();
    float inv = 1.f / fmaxf(redv[0] + redv[1] + redv[2] + redv[3], 1.f);
#pragma unroll
    for (int c = 0; c < 8; ++c)
      motif[(size_t)s * kN + t + c * 256] = sv[c] * inv;
  } else {
    // ---------------- layer-1 GEMM tile + src/dst epilogue ----------------
    int idx = g9;                    // [0, 256)
    int hop = idx >> 7;
    int rem = idx & 127;
    int row0 = (rem >> 2) * 64, col0 = (rem & 3) * 64;
    const float* B = l1w + (size_t)hop * kIN * kC1;
    float* Cz = hx1 + (size_t)hop * kN * kC1;
    float (*As)[65] = (float(*)[65])smem;
    float (*Bs)[65] = (float(*)[65])(smem + 4160);
    int tx = t & 15, ty = t >> 4;
    float acc[4][4] = {};
    for (int k0 = 0; k0 < kIN; k0 += 16) {
      {
        int e = t * 4;
        int m = e >> 4, kk = e & 15;
        float4 va = *reinterpret_cast<const float4*>(x + (size_t)(row0 + m) * kIN + k0 + kk);
        As[kk + 0][m] = va.x; As[kk + 1][m] = va.y;
        As[kk + 2][m] = va.z; As[kk + 3][m] = va.w;
      }
      {
        int kb = t >> 4, nb = (t & 15) * 4;
        float4 vb = *reinterpret_cast<const float4*>(B + (size_t)(k0 + kb) * kC1 + col0 + nb);
        Bs[kb][nb + 0] = vb.x; Bs[kb][nb + 1] = vb.y;
        Bs[kb][nb + 2] = vb.z; Bs[kb][nb + 3] = vb.w;
      }
      __syncthreads();
#pragma unroll
      for (int kk2 = 0; kk2 < 16; ++kk2) {
        float a[4], b[4];
#pragma unroll
        for (int i = 0; i < 4; ++i) a[i] = As[kk2][ty * 4 + i];
#pragma unroll
        for (int j = 0; j < 4; ++j) b[j] = Bs[kk2][tx * 4 + j];
#pragma unroll
        for (int i = 0; i < 4; ++i)
#pragma unroll
          for (int j = 0; j < 4; ++j) acc[i][j] += a[i] * b[j];
      }
      __syncthreads();
    }
#pragma unroll
    for (int i = 0; i < 4; ++i)
#pragma unroll
      for (int j = 0; j < 4; ++j)
        Cz[(size_t)(row0 + ty * 4 + i) * kC1 + col0 + tx * 4 + j] = acc[i][j];
    int h = col0 >> 6;
    float as_[4], ad_[4];
#pragma unroll
    for (int j = 0; j < 4; ++j) {
      as_[j] = l1as[hop * kC1 + col0 + tx * 4 + j];
      ad_[j] = l1ad[hop * kC1 + col0 + tx * 4 + j];
    }
#pragma unroll
    for (int i = 0; i < 4; ++i) {
      float ps = acc[i][0] * as_[0] + acc[i][1] * as_[1] +
                 acc[i][2] * as_[2] + acc[i][3] * as_[3];
      float pd = acc[i][0] * ad_[0] + acc[i][1] * ad_[1] +
                 acc[i][2] * ad_[2] + acc[i][3] * ad_[3];
#pragma unroll
      for (int o = 1; o < 16; o <<= 1) {
        ps += __shfl_xor(ps, o);
        pd += __shfl_xor(pd, o);
      }
      if (tx == 0) {
        int n = row0 + ty * 4 + i;
        ss1[((size_t)hop * kN + n) * 4 + h] = ps;
        sd1[((size_t)hop * kN + n) * 4 + h] = pd;
      }
    }
  }
}

// layer-2 GEMM (z: 0,1 = hops via l2w with src/dst epilogue; 2 = res via l2rw)
__global__ __launch_bounds__(256) void gemm2(
    const float* __restrict__ A, const float* __restrict__ l2w,
    const float* __restrict__ l2rw, float* __restrict__ C,
    const float* __restrict__ attS, const float* __restrict__ attD,
    float* __restrict__ ssO, float* __restrict__ sdO) {
  int z = blockIdx.z;
  const float* B = (z < 2) ? l2w + (size_t)z * kC1 * kC2 : l2rw;
  float* Cz = C + (size_t)z * kN * kC2;
  __shared__ float As[16][65];
  __shared__ float Bs[16][65];
  int t = threadIdx.x;
  int tx = t & 15, ty = t >> 4;
  int row0 = blockIdx.y * 64;
  float acc[4][4] = {};
  for (int k0 = 0; k0 < kC1; k0 += 16) {
    {
      int e = t * 4;
      int m = e >> 4, kk = e & 15;
      float4 va = *reinterpret_cast<const float4*>(A + (size_t)(row0 + m) * kC1 + k0 + kk);
      As[kk + 0][m] = va.x; As[kk + 1][m] = va.y;
      As[kk + 2][m] = va.z; As[kk + 3][m] = va.w;
    }
    {
      int kb = t >> 4, nb = (t & 15) * 4;
      float4 vb = *reinterpret_cast<const float4*>(B + (size_t)(k0 + kb) * kC2 + nb);
      Bs[kb][nb + 0] = vb.x; Bs[kb][nb + 1] = vb.y;
      Bs[kb][nb + 2] = vb.z; Bs[kb][nb + 3] = vb.w;
    }
    __syncthreads();
#pragma unroll
    for (int kk2 = 0; kk2 < 16; ++kk2) {
      float a[4], b[4];
#pragma unroll
      for (int i = 0; i < 4; ++i) a[i] = As[kk2][ty * 4 + i];
#pragma unroll
      for (int j = 0; j < 4; ++j) b[j] = Bs[kk2][tx * 4 + j];
#pragma unroll
      for (int i = 0; i < 4; ++i)
#pragma unroll
        for (int j = 0; j < 4; ++j) acc[i][j] += a[i] * b[j];
    }
    __syncthreads();
  }
#pragma unroll
  for (int i = 0; i < 4; ++i)
#pragma unroll
    for (int j = 0; j < 4; ++j)
      Cz[(size_t)(row0 + ty * 4 + i) * kC2 + tx * 4 + j] = acc[i][j];
  if (z < 2) {
    float as_[4], ad_[4];
#pragma unroll
    for (int j = 0; j < 4; ++j) {
      as_[j] = attS[z * kC2 + tx * 4 + j];
      ad_[j] = attD[z * kC2 + tx * 4 + j];
    }
#pragma unroll
    for (int i = 0; i < 4; ++i) {
      float ps = acc[i][0] * as_[0] + acc[i][1] * as_[1] +
                 acc[i][2] * as_[2] + acc[i][3] * as_[3];
      float pd = acc[i][0] * ad_[0] + acc[i][1] * ad_[1] +
                 acc[i][2] * ad_[2] + acc[i][3] * ad_[3];
#pragma unroll
      for (int o = 1; o < 16; o <<= 1) {
        ps += __shfl_xor(ps, o);
        pd += __shfl_xor(pd, o);
      }
      if (tx == 0) {
        int n = row0 + ty * 4 + i;
        ssO[(size_t)z * kN + n] = ps;
        sdO[(size_t)z * kN + n] = pd;
      }
    }
  }
}

// layer-1 aggregation, fused stats; float4 FMA layout (4 s-slots x 64 quads).
__global__ __launch_bounds__(256) void agg_l1(
    const float* __restrict__ hx,      // [2][N][256]
    const float* __restrict__ ssrc,    // [2][N][4]
    const float* __restrict__ sdst,    // [2][N][4]
    const float* __restrict__ motif,
    const unsigned long long* __restrict__ colbitsT,
    const unsigned long long* __restrict__ colbits2T,
    const float* __restrict__ hop_att,
    const float* __restrict__ bias,
    float* __restrict__ hbuf) {
  int d = blockIdx.x;
  int t = threadIdx.x;
  int lane = t & 63;
  int h = t >> 6;       // stats wave == head; also s-slot for FMA
  int cq = lane;        // channel quad [0,64)
  int hq = cq >> 4;     // head of this quad
  __shared__ unsigned short slist[kN];
  __shared__ float w_lds[64 * 4];
  __shared__ int s_total;
  __shared__ float4 red4[4][64];
  float a0 = hop_att[0], a1 = hop_att[1];
  float mxa = fmaxf(a0, a1);
  float e0 = __expf(a0 - mxa), e1 = __expf(a1 - mxa);
  float wh0 = e0 / (e0 + e1), wh1 = e1 / (e0 + e1);
  float4 acc4 = make_float4(0.f, 0.f, 0.f, 0.f);
  for (int hop = 0; hop < 2; ++hop) {
    const unsigned long long* cm = hop ? colbits2T : colbitsT;
    if (t < 64) {
      unsigned long long word = (lane < kWords) ? cm[(size_t)lane * kN + d] : 0ull;
      if (lane == (d >> 6)) word |= 1ull << (d & 63);
      int cnt = __popcll(word);
      int inc = cnt;
      for (int o = 1; o < 64; o <<= 1) { int v = __shfl_up(inc, o); if (lane >= o) inc += v; }
      if (lane == 63) s_total = inc;
      int off = inc - cnt;
      int base = lane * 64;
      while (word) {
        int b = __builtin_ctzll(word);
        word &= word - 1;
        slist[off++] = (unsigned short)(base + b);
      }
    }
    __syncthreads();
    int total = s_total;
    float sd = sdst[((size_t)hop * kN + d) * 4 + h];
    const float4* hx4 = reinterpret_cast<const float4*>(hx + (size_t)hop * kN * kC1);
    const float* ssp = ssrc + (size_t)hop * kN * 4;
    // fused stats: wave h computes online-softmax stats for head h
    float m1 = -3.0e38f, l1v = 0.f, m2 = -3.0e38f, l2v = 0.f;
    for (int q = lane; q < total; q += 64) {
      int s = slist[q];
      float mv = motif[(size_t)s * kN + d];
      float v = ssp[s * 4 + h] + sd;
      onl(m1, l1v, leakyf(v));
      onl(m2, l2v, leakyf(v * mv));
    }
#pragma unroll
    for (int o = 1; o < 64; o <<= 1) {
      float mm = __shfl_xor(m1, o), ll = __shfl_xor(l1v, o);
      mergeml(m1, l1v, mm, ll);
      float mm2 = __shfl_xor(m2, o), ll2 = __shfl_xor(l2v, o);
      mergeml(m2, l2v, mm2, ll2);
    }
    float il1 = 1.f / l1v, il2 = 1.f / l2v;
    float wh = hop ? wh1 : wh0;
    for (int c0 = 0; c0 < total; c0 += 64) {
      int nsi = min(64, total - c0);
      if (lane < nsi) {
        int s = slist[c0 + lane];
        float mv = motif[(size_t)s * kN + d];
        float v = ssp[s * 4 + h] + sd;
        w_lds[lane * 4 + h] = (0.5f * __expf(leakyf(v) - m1) * il1 +
                               0.5f * __expf(leakyf(v * mv) - m2) * il2) * wh;
      }
      __syncthreads();
      int q = h;
      for (; q + 4 < nsi; q += 8) {
        int s0 = slist[c0 + q], s1 = slist[c0 + q + 4];
        float4 r0 = hx4[(size_t)s0 * 64 + cq];
        float4 r1 = hx4[(size_t)s1 * 64 + cq];
        float w0 = w_lds[q * 4 + hq], w1 = w_lds[(q + 4) * 4 + hq];
        acc4.x += w0 * r0.x + w1 * r1.x;
        acc4.y += w0 * r0.y + w1 * r1.y;
        acc4.z += w0 * r0.z + w1 * r1.z;
        acc4.w += w0 * r0.w + w1 * r1.w;
      }
      if (q < nsi) {
        int s0 = slist[c0 + q];
        float4 r0 = hx4[(size_t)s0 * 64 + cq];
        float w0 = w_lds[q * 4 + hq];
        acc4.x += w0 * r0.x; acc4.y += w0 * r0.y;
        acc4.z += w0 * r0.z; acc4.w += w0 * r0.w;
      }
      __syncthreads();
    }
    __syncthreads();
  }
  red4[h][cq] = acc4;
  __syncthreads();
  if (t < 64) {
    float4 a = red4[0][t], b = red4[1][t], c = red4[2][t], e = red4[3][t];
    float4 bv = reinterpret_cast<const float4*>(bias)[t];
    float4 v;
    v.x = a.x + b.x + c.x + e.x + bv.x;
    v.y = a.y + b.y + c.y + e.y + bv.y;
    v.z = a.z + b.z + c.z + e.z + bv.z;
    v.w = a.w + b.w + c.w + e.w + bv.w;
    v.x = v.x > 0.f ? v.x : __expf(v.x) - 1.f;
    v.y = v.y > 0.f ? v.y : __expf(v.y) - 1.f;
    v.z = v.z > 0.f ? v.z : __expf(v.z) - 1.f;
    v.w = v.w > 0.f ? v.w : __expf(v.w) - 1.f;
    reinterpret_cast<float4*>(hbuf)[(size_t)d * 64 + t] = v;
  }
}

// layer-2 aggregation, fused stats; float4 FMA layout (16 s-slots x 16 quads);
// fused residual + LayerNorm + bias -> output. grid = N.
__global__ __launch_bounds__(256) void agg_l2(
    const float* __restrict__ hx,      // [2][N][64]
    const float* __restrict__ ssrc,    // [2][N]
    const float* __restrict__ sdst,    // [2][N]
    const float* __restrict__ motif,
    const unsigned long long* __restrict__ colbitsT,
    const unsigned long long* __restrict__ colbits2T,
    const float* __restrict__ hop_att,
    const float* __restrict__ res,     // [N][64]
    const float* __restrict__ lns, const float* __restrict__ lnb,
    const float* __restrict__ l2b,
    float* __restrict__ out) {
  int d = blockIdx.x;
  int t = threadIdx.x;
  int lane = t & 63;
  int g = t >> 6;      // wave id (stats)
  int cq = t & 15;     // channel quad [0,16)
  int sg = t >> 4;     // s-slot [0,16)
  __shared__ unsigned short slist[kN];
  __shared__ float w_lds[64];
  __shared__ int s_total;
  __shared__ float4 red4[16][16];
  __shared__ float out_lds[64];
  __shared__ float smst[4][4];
  float a0 = hop_att[0], a1 = hop_att[1];
  float mxa = fmaxf(a0, a1);
  float e0 = __expf(a0 - mxa), e1 = __expf(a1 - mxa);
  float wh0 = e0 / (e0 + e1), wh1 = e1 / (e0 + e1);
  float4 acc4 = make_float4(0.f, 0.f, 0.f, 0.f);
  for (int hop = 0; hop < 2; ++hop) {
    const unsigned long long* cm = hop ? colbits2T : colbitsT;
    if (t < 64) {
      unsigned long long word = (lane < kWords) ? cm[(size_t)lane * kN + d] : 0ull;
      if (lane == (d >> 6)) word |= 1ull << (d & 63);
      int cnt = __popcll(word);
      int inc = cnt;
      for (int o = 1; o < 64; o <<= 1) { int v = __shfl_up(inc, o); if (lane >= o) inc += v; }
      if (lane == 63) s_total = inc;
      int off = inc - cnt;
      int base = lane * 64;
      while (word) {
        int b = __builtin_ctzll(word);
        word &= word - 1;
        slist[off++] = (unsigned short)(base + b);
      }
    }
    __syncthreads();
    int total = s_total;
    float sd = sdst[(size_t)hop * kN + d];
    const float4* hx4 = reinterpret_cast<const float4*>(hx + (size_t)hop * kN * kC2);
    const float* ssp = ssrc + (size_t)hop * kN;
    float m1 = -3.0e38f, l1v = 0.f, m2 = -3.0e38f, l2v = 0.f;
    for (int q = t; q < total; q += 256) {
      int s = slist[q];
      float mv = motif[(size_t)s * kN + d];
      float v = ssp[s] + sd;
      onl(m1, l1v, leakyf(v));
      onl(m2, l2v, leakyf(v * mv));
    }
#pragma unroll
    for (int o = 1; o < 64; o <<= 1) {
      float mm = __shfl_xor(m1, o), ll = __shfl_xor(l1v, o);
      mergeml(m1, l1v, mm, ll);
      float mm2 = __shfl_xor(m2, o), ll2 = __shfl_xor(l2v, o);
      mergeml(m2, l2v, mm2, ll2);
    }
    if (lane == 0) {
      smst[g][0] = m1; smst[g][1] = l1v; smst[g][2] = m2; smst[g][3] = l2v;
    }
    __syncthreads();
    float M1 = -3.0e38f, L1 = 0.f, M2 = -3.0e38f, L2 = 0.f;
#pragma unroll
    for (int gg = 0; gg < 4; ++gg) {
      mergeml(M1, L1, smst[gg][0], smst[gg][1]);
      mergeml(M2, L2, smst[gg][2], smst[gg][3]);
    }
    float il1 = 1.f / L1, il2 = 1.f / L2;
    float wh = hop ? wh1 : wh0;
    for (int c0 = 0; c0 < total; c0 += 64) {
      int nsi = min(64, total - c0);
      if (t < nsi) {
        int s = slist[c0 + t];
        float mv = motif[(size_t)s * kN + d];
        float v = ssp[s] + sd;
        w_lds[t] = (0.5f * __expf(leakyf(v) - M1) * il1 +
                    0.5f * __expf(leakyf(v * mv) - M2) * il2) * wh;
      }
      __syncthreads();
      int q = sg;
      for (; q + 16 < nsi; q += 32) {
        int s0 = slist[c0 + q], s1 = slist[c0 + q + 16];
        float4 r0 = hx4[(size_t)s0 * 16 + cq];
        float4 r1 = hx4[(size_t)s1 * 16 + cq];
        float w0 = w_lds[q], w1 = w_lds[q + 16];
        acc4.x += w0 * r0.x + w1 * r1.x;
        acc4.y += w0 * r0.y + w1 * r1.y;
        acc4.z += w0 * r0.z + w1 * r1.z;
        acc4.w += w0 * r0.w + w1 * r1.w;
      }
      if (q < nsi) {
        int s0 = slist[c0 + q];
        float4 r0 = hx4[(size_t)s0 * 16 + cq];
        float w0 = w_lds[q];
        acc4.x += w0 * r0.x; acc4.y += w0 * r0.y;
        acc4.z += w0 * r0.z; acc4.w += w0 * r0.w;
      }
      __syncthreads();
    }
    __syncthreads();
  }
  red4[sg][cq] = acc4;
  __syncthreads();
  if (t < 16) {
    float4 v = make_float4(0.f, 0.f, 0.f, 0.f);
#pragma unroll
    for (int q = 0; q < 16; ++q) {
      float4 a = red4[q][t];
      v.x += a.x; v.y += a.y; v.z += a.z; v.w += a.w;
    }
    out_lds[t * 4 + 0] = v.x;
    out_lds[t * 4 + 1] = v.y;
    out_lds[t * 4 + 2] = v.z;
    out_lds[t * 4 + 3] = v.w;
  }
  __syncthreads();
  if (t < 64) {
    float v = out_lds[t] + res[(size_t)d * kC2 + t];
    float s = v;
    for (int o = 32; o; o >>= 1) s += __shfl_xor(s, o);
    float mu = s * (1.f / kC2);
    float dv = v - mu;
    float q = dv * dv;
    for (int o = 32; o; o >>= 1) q += __shfl_xor(q, o);
    float var = q * (1.f / kC2);
    out[(size_t)d * kC2 + t] = dv * rsqrtf(var + kLnEps) * lns[t] + lnb[t] + l2b[t];
  }
}

}  // namespace

extern "C" void kernel_launch(void* const* d_in, const int* in_sizes, int n_in,
                              void* d_out, int out_size, void* d_ws, size_t ws_size,
                              hipStream_t stream) {
  const float* x    = (const float*)d_in[0];
  const int*   ei   = (const int*)d_in[1];
  const float* l1w  = (const float*)d_in[2];
  const float* l1as = (const float*)d_in[3];
  const float* l1ad = (const float*)d_in[4];
  const float* l1ha = (const float*)d_in[5];
  const float* l1b  = (const float*)d_in[6];
  const float* l2w  = (const float*)d_in[7];
  const float* l2as = (const float*)d_in[8];
  const float* l2ad = (const float*)d_in[9];
  const float* l2ha = (const float*)d_in[10];
  const float* l2rw = (const float*)d_in[11];
  const float* lns  = (const float*)d_in[12];
  const float* lnb  = (const float*)d_in[13];
  const float* l2b  = (const float*)d_in[14];
  int E = in_sizes[1] / 2;

  // ---- workspace layout (bytes) ----
  size_t o = 0;
  auto take = [&](size_t bytes) { size_t r = o; o += (bytes + 255) & ~(size_t)255; return r; };
  size_t oRB  = take((size_t)kN * kWords * 8);      // rowbits
  size_t oCB  = take((size_t)kWords * kN * 8);      // colbitsT
  size_t oCB2 = take((size_t)kWords * kN * 8);      // colbits2T (A2 structure)
  size_t zEnd = o;                                  // zero region end
  size_t oMF  = take((size_t)kN * kN * 4);
  size_t oHX1 = take((size_t)2 * kN * kC1 * 4);
  size_t oH   = take((size_t)kN * kC1 * 4);
  size_t oHX2 = take((size_t)3 * kN * kC2 * 4);     // hop0 | hop1 | res
  size_t oSS1 = take((size_t)2 * kN * 4 * 4);
  size_t oSD1 = take((size_t)2 * kN * 4 * 4);
  size_t oSS2 = take((size_t)2 * kN * 4);
  size_t oSD2 = take((size_t)2 * kN * 4);
  if (ws_size < o) return;  // insufficient scratch; fail visibly

  char* w = (char*)d_ws;
  unsigned long long* rowbits = (unsigned long long*)(w + oRB);
  unsigned long long* colbitsT = (unsigned long long*)(w + oCB);
  unsigned long long* colbits2T = (unsigned long long*)(w + oCB2);
  float* motif = (float*)(w + oMF);
  float* hx1 = (float*)(w + oHX1);
  float* hbuf = (float*)(w + oH);
  float* hx2 = (float*)(w + oHX2);
  float* res = hx2 + (size_t)2 * kN * kC2;
  float* ss1 = (float*)(w + oSS1);
  float* sd1 = (float*)(w + oSD1);
  float* ss2 = (float*)(w + oSS2);
  float* sd2 = (float*)(w + oSD2);

  hipMemsetAsync(d_ws, 0, zEnd, stream);

  build_bits<<<(E + 255) / 256, 256, 0, stream>>>(ei, E, rowbits, colbitsT);

  // motif rows interleaved with layer-1 GEMM tiles (every 9th block)
  fat1<<<kN + 256, 256, 0, stream>>>(rowbits, motif, colbits2T,
                                     x, l1w, hx1, l1as, l1ad, ss1, sd1);

  agg_l1<<<kN, 256, 0, stream>>>(hx1, ss1, sd1, motif, colbitsT, colbits2T,
                                 l1ha, l1b, hbuf);

  gemm2<<<dim3(1, kN / 64, 3), 256, 0, stream>>>(hbuf, l2w, l2rw, hx2,
                                                 l2as, l2ad, ss2, sd2);

  agg_l2<<<kN, 256, 0, stream>>>(hx2, ss2, sd2, motif, colbitsT, colbits2T,
                                 l2ha, res, lns, lnb, l2b, (float*)d_out);
}

// Round 11
// 188.367 us; speedup vs baseline: 1.2859x; 1.1103x over previous
//
#include <hip/hip_runtime.h>

namespace {

constexpr int kN = 2048;
constexpr int kWords = kN / 64;   // 32
constexpr int kC1 = 256;          // HEADS*HID
constexpr int kC2 = 64;           // OUT_CH
constexpr int kIN = 512;
constexpr float kNegSlope = 0.2f;
constexpr float kLnEps = 1e-5f;

__device__ __forceinline__ float leakyf(float v) {
  return v >= 0.f ? v : kNegSlope * v;
}
__device__ __forceinline__ void onl(float& m, float& l, float v) {
  if (v > m) { l = l * __expf(m - v) + 1.f; m = v; }
  else       { l += __expf(v - m); }
}
__device__ __forceinline__ void mergeml(float& M, float& L, float m, float l) {
  if (m > M) { L = L * __expf(M - m) + l; M = m; }
  else       { L += l * __expf(m - M); }
}

// ---------------- adjacency bitsets ----------------
__global__ void build_bits(const int* __restrict__ ei, int E,
                           unsigned long long* rowbits, unsigned long long* colbitsT) {
  int e = blockIdx.x * 256 + threadIdx.x;
  if (e >= E) return;
  int s = ei[e], d = ei[E + e];
  atomicOr(&rowbits[(size_t)s * kWords + (d >> 6)], 1ull << (d & 63));
  atomicOr(&colbitsT[(size_t)(s >> 6) * kN + d], 1ull << (s & 63));
}

// Tiled popcount-GEMM: A2[s][d] = popc(row_s & col_d) for a 64x64 tile.
// Also emits colbits2T structure words (tile exclusively owns them -> plain
// stores, no atomics, no pre-zeroing).
__global__ __launch_bounds__(256) void a2_tiled(
    const unsigned long long* __restrict__ rowbits,
    const unsigned long long* __restrict__ colbitsT,
    unsigned short* __restrict__ A2,
    unsigned long long* __restrict__ colbits2T) {
  int bx = blockIdx.x, by = blockIdx.y;   // d-tile, s-tile
  int t = threadIdx.x;
  __shared__ unsigned long long rb[64][33];  // padded: conflict-free
  __shared__ unsigned long long cb[32][64];
  __shared__ unsigned long long cw[64];
  int s0 = by * 64, d0 = bx * 64;
  for (int i = t; i < 64 * 32; i += 256) {
    int ss = i >> 5, w = i & 31;
    rb[ss][w] = rowbits[(size_t)(s0 + ss) * kWords + w];
  }
  for (int i = t; i < 32 * 64; i += 256) {
    int w = i >> 6, dd = i & 63;
    cb[w][dd] = colbitsT[(size_t)w * kN + d0 + dd];
  }
  if (t < 64) cw[t] = 0ull;
  __syncthreads();
  int tx = t & 15, ty4 = (t >> 4) * 4;
  int acc[4][4] = {};
#pragma unroll 4
  for (int w = 0; w < 32; ++w) {
    unsigned long long r0 = rb[ty4 + 0][w], r1 = rb[ty4 + 1][w];
    unsigned long long r2 = rb[ty4 + 2][w], r3 = rb[ty4 + 3][w];
    unsigned long long c0 = cb[w][tx], c1 = cb[w][tx + 16];
    unsigned long long c2 = cb[w][tx + 32], c3 = cb[w][tx + 48];
    acc[0][0] += __popcll(r0 & c0); acc[0][1] += __popcll(r0 & c1);
    acc[0][2] += __popcll(r0 & c2); acc[0][3] += __popcll(r0 & c3);
    acc[1][0] += __popcll(r1 & c0); acc[1][1] += __popcll(r1 & c1);
    acc[1][2] += __popcll(r1 & c2); acc[1][3] += __popcll(r1 & c3);
    acc[2][0] += __popcll(r2 & c0); acc[2][1] += __popcll(r2 & c1);
    acc[2][2] += __popcll(r2 & c2); acc[2][3] += __popcll(r2 & c3);
    acc[3][0] += __popcll(r3 & c0); acc[3][1] += __popcll(r3 & c1);
    acc[3][2] += __popcll(r3 & c2); acc[3][3] += __popcll(r3 & c3);
  }
#pragma unroll
  for (int i = 0; i < 4; ++i)
#pragma unroll
    for (int j = 0; j < 4; ++j)
      A2[(size_t)(s0 + ty4 + i) * kN + d0 + tx + 16 * j] = (unsigned short)acc[i][j];
#pragma unroll
  for (int j = 0; j < 4; ++j) {
    unsigned long long m = 0;
#pragma unroll
    for (int i = 0; i < 4; ++i)
      if (acc[i][j]) m |= 1ull << (ty4 + i);
    if (m) atomicOr(&cw[tx + 16 * j], m);
  }
  __syncthreads();
  if (t < 64) colbits2T[(size_t)by * kN + d0 + t] = cw[t];
}

// A3 row s = sum_{j in rowA[s]} A2[j,:], dense coalesced uint4 packed-u16
// adds (sums <= ~640, no carry); normalize -> motif row. One block per s.
__global__ __launch_bounds__(256) void a3_dense(
    const unsigned long long* __restrict__ rowbits,
    const unsigned short* __restrict__ A2,
    float* __restrict__ motif) {
  int s = blockIdx.x;
  int t = threadIdx.x;
  int lane = t & 63;
  __shared__ unsigned short jl[kN];
  __shared__ int jtot_s;
  __shared__ float redv[4];
  if (t < 64) {
    unsigned long long word = (lane < kWords) ? rowbits[(size_t)s * kWords + lane] : 0ull;
    int c = __popcll(word);
    int inc = c;
    for (int o = 1; o < 64; o <<= 1) { int v = __shfl_up(inc, o); if (lane >= o) inc += v; }
    if (lane == 63) jtot_s = inc;
    int off = inc - c;
    int base = lane * 64;
    while (word) {
      int b = __builtin_ctzll(word);
      word &= word - 1;
      jl[off++] = (unsigned short)(base + b);
    }
  }
  __syncthreads();
  int jtot = jtot_s;
  const uint4* a2v = reinterpret_cast<const uint4*>(A2);
  uint4 acc = make_uint4(0u, 0u, 0u, 0u);
  int ji = 0;
  for (; ji + 4 <= jtot; ji += 4) {
    uint4 v0 = a2v[(size_t)jl[ji + 0] * 128 + t];
    uint4 v1 = a2v[(size_t)jl[ji + 1] * 128 + t];
    uint4 v2 = a2v[(size_t)jl[ji + 2] * 128 + t];
    uint4 v3 = a2v[(size_t)jl[ji + 3] * 128 + t];
    acc.x += v0.x + v1.x + v2.x + v3.x;
    acc.y += v0.y + v1.y + v2.y + v3.y;
    acc.z += v0.z + v1.z + v2.z + v3.z;
    acc.w += v0.w + v1.w + v2.w + v3.w;
  }
  for (; ji < jtot; ++ji) {
    uint4 v = a2v[(size_t)jl[ji] * 128 + t];
    acc.x += v.x; acc.y += v.y; acc.z += v.z; acc.w += v.w;
  }
  float f[8];
  f[0] = (float)(acc.x & 0xffffu); f[1] = (float)(acc.x >> 16);
  f[2] = (float)(acc.y & 0xffffu); f[3] = (float)(acc.y >> 16);
  f[4] = (float)(acc.z & 0xffffu); f[5] = (float)(acc.z >> 16);
  f[6] = (float)(acc.w & 0xffffu); f[7] = (float)(acc.w >> 16);
  float tot = 0.f;
#pragma unroll
  for (int c = 0; c < 8; ++c) tot += f[c];
  for (int o = 32; o; o >>= 1) tot += __shfl_xor(tot, o);
  if (lane == 0) redv[t >> 6] = tot;
  __syncthreads();
  float inv = 1.f / fmaxf(redv[0] + redv[1] + redv[2] + redv[3], 1.f);
  float4 lo = make_float4(f[0] * inv, f[1] * inv, f[2] * inv, f[3] * inv);
  float4 hi = make_float4(f[4] * inv, f[5] * inv, f[6] * inv, f[7] * inv);
  float4* mp = reinterpret_cast<float4*>(motif + (size_t)s * kN);
  mp[t * 2 + 0] = lo;
  mp[t * 2 + 1] = hi;
}

// layer-1 GEMM with fused s_src/s_dst epilogue. grid (4, 32, 2)
__global__ __launch_bounds__(256) void gemm1(
    const float* __restrict__ x, const float* __restrict__ l1w,
    float* __restrict__ hx1,
    const float* __restrict__ l1as, const float* __restrict__ l1ad,
    float* __restrict__ ss1, float* __restrict__ sd1) {
  int hop = blockIdx.z;
  int row0 = blockIdx.y * 64, col0 = blockIdx.x * 64;
  const float* B = l1w + (size_t)hop * kIN * kC1;
  float* Cz = hx1 + (size_t)hop * kN * kC1;
  __shared__ float As[16][65];
  __shared__ float Bs[16][65];
  int t = threadIdx.x;
  int tx = t & 15, ty = t >> 4;
  float acc[4][4] = {};
  for (int k0 = 0; k0 < kIN; k0 += 16) {
    {
      int e = t * 4;
      int m = e >> 4, kk = e & 15;
      float4 va = *reinterpret_cast<const float4*>(x + (size_t)(row0 + m) * kIN + k0 + kk);
      As[kk + 0][m] = va.x; As[kk + 1][m] = va.y;
      As[kk + 2][m] = va.z; As[kk + 3][m] = va.w;
    }
    {
      int kb = t >> 4, nb = (t & 15) * 4;
      float4 vb = *reinterpret_cast<const float4*>(B + (size_t)(k0 + kb) * kC1 + col0 + nb);
      Bs[kb][nb + 0] = vb.x; Bs[kb][nb + 1] = vb.y;
      Bs[kb][nb + 2] = vb.z; Bs[kb][nb + 3] = vb.w;
    }
    __syncthreads();
#pragma unroll
    for (int kk2 = 0; kk2 < 16; ++kk2) {
      float a[4], b[4];
#pragma unroll
      for (int i = 0; i < 4; ++i) a[i] = As[kk2][ty * 4 + i];
#pragma unroll
      for (int j = 0; j < 4; ++j) b[j] = Bs[kk2][tx * 4 + j];
#pragma unroll
      for (int i = 0; i < 4; ++i)
#pragma unroll
        for (int j = 0; j < 4; ++j) acc[i][j] += a[i] * b[j];
    }
    __syncthreads();
  }
#pragma unroll
  for (int i = 0; i < 4; ++i)
#pragma unroll
    for (int j = 0; j < 4; ++j)
      Cz[(size_t)(row0 + ty * 4 + i) * kC1 + col0 + tx * 4 + j] = acc[i][j];
  int h = col0 >> 6;
  float as_[4], ad_[4];
#pragma unroll
  for (int j = 0; j < 4; ++j) {
    as_[j] = l1as[hop * kC1 + col0 + tx * 4 + j];
    ad_[j] = l1ad[hop * kC1 + col0 + tx * 4 + j];
  }
#pragma unroll
  for (int i = 0; i < 4; ++i) {
    float ps = acc[i][0] * as_[0] + acc[i][1] * as_[1] +
               acc[i][2] * as_[2] + acc[i][3] * as_[3];
    float pd = acc[i][0] * ad_[0] + acc[i][1] * ad_[1] +
               acc[i][2] * ad_[2] + acc[i][3] * ad_[3];
#pragma unroll
    for (int o = 1; o < 16; o <<= 1) {
      ps += __shfl_xor(ps, o);
      pd += __shfl_xor(pd, o);
    }
    if (tx == 0) {
      int n = row0 + ty * 4 + i;
      ss1[((size_t)hop * kN + n) * 4 + h] = ps;
      sd1[((size_t)hop * kN + n) * 4 + h] = pd;
    }
  }
}

// layer-2 GEMM (z: 0,1 = hops via l2w with src/dst epilogue; 2 = res via l2rw)
__global__ __launch_bounds__(256) void gemm2(
    const float* __restrict__ A, const float* __restrict__ l2w,
    const float* __restrict__ l2rw, float* __restrict__ C,
    const float* __restrict__ attS, const float* __restrict__ attD,
    float* __restrict__ ssO, float* __restrict__ sdO) {
  int z = blockIdx.z;
  const float* B = (z < 2) ? l2w + (size_t)z * kC1 * kC2 : l2rw;
  float* Cz = C + (size_t)z * kN * kC2;
  __shared__ float As[16][65];
  __shared__ float Bs[16][65];
  int t = threadIdx.x;
  int tx = t & 15, ty = t >> 4;
  int row0 = blockIdx.y * 64;
  float acc[4][4] = {};
  for (int k0 = 0; k0 < kC1; k0 += 16) {
    {
      int e = t * 4;
      int m = e >> 4, kk = e & 15;
      float4 va = *reinterpret_cast<const float4*>(A + (size_t)(row0 + m) * kC1 + k0 + kk);
      As[kk + 0][m] = va.x; As[kk + 1][m] = va.y;
      As[kk + 2][m] = va.z; As[kk + 3][m] = va.w;
    }
    {
      int kb = t >> 4, nb = (t & 15) * 4;
      float4 vb = *reinterpret_cast<const float4*>(B + (size_t)(k0 + kb) * kC2 + nb);
      Bs[kb][nb + 0] = vb.x; Bs[kb][nb + 1] = vb.y;
      Bs[kb][nb + 2] = vb.z; Bs[kb][nb + 3] = vb.w;
    }
    __syncthreads();
#pragma unroll
    for (int kk2 = 0; kk2 < 16; ++kk2) {
      float a[4], b[4];
#pragma unroll
      for (int i = 0; i < 4; ++i) a[i] = As[kk2][ty * 4 + i];
#pragma unroll
      for (int j = 0; j < 4; ++j) b[j] = Bs[kk2][tx * 4 + j];
#pragma unroll
      for (int i = 0; i < 4; ++i)
#pragma unroll
        for (int j = 0; j < 4; ++j) acc[i][j] += a[i] * b[j];
    }
    __syncthreads();
  }
#pragma unroll
  for (int i = 0; i < 4; ++i)
#pragma unroll
    for (int j = 0; j < 4; ++j)
      Cz[(size_t)(row0 + ty * 4 + i) * kC2 + tx * 4 + j] = acc[i][j];
  if (z < 2) {
    float as_[4], ad_[4];
#pragma unroll
    for (int j = 0; j < 4; ++j) {
      as_[j] = attS[z * kC2 + tx * 4 + j];
      ad_[j] = attD[z * kC2 + tx * 4 + j];
    }
#pragma unroll
    for (int i = 0; i < 4; ++i) {
      float ps = acc[i][0] * as_[0] + acc[i][1] * as_[1] +
                 acc[i][2] * as_[2] + acc[i][3] * as_[3];
      float pd = acc[i][0] * ad_[0] + acc[i][1] * ad_[1] +
                 acc[i][2] * ad_[2] + acc[i][3] * ad_[3];
#pragma unroll
      for (int o = 1; o < 16; o <<= 1) {
        ps += __shfl_xor(ps, o);
        pd += __shfl_xor(pd, o);
      }
      if (tx == 0) {
        int n = row0 + ty * 4 + i;
        ssO[(size_t)z * kN + n] = ps;
        sdO[(size_t)z * kN + n] = pd;
      }
    }
  }
}

// layer-1 aggregation, fused stats; float4 FMA layout (4 s-slots x 64 quads).
__global__ __launch_bounds__(256) void agg_l1(
    const float* __restrict__ hx,      // [2][N][256]
    const float* __restrict__ ssrc,    // [2][N][4]
    const float* __restrict__ sdst,    // [2][N][4]
    const float* __restrict__ motif,
    const unsigned long long* __restrict__ colbitsT,
    const unsigned long long* __restrict__ colbits2T,
    const float* __restrict__ hop_att,
    const float* __restrict__ bias,
    float* __restrict__ hbuf) {
  int d = blockIdx.x;
  int t = threadIdx.x;
  int lane = t & 63;
  int h = t >> 6;       // stats wave == head; also s-slot for FMA
  int cq = lane;        // channel quad [0,64)
  int hq = cq >> 4;     // head of this quad
  __shared__ unsigned short slist[kN];
  __shared__ float w_lds[64 * 4];
  __shared__ int s_total;
  __shared__ float4 red4[4][64];
  float a0 = hop_att[0], a1 = hop_att[1];
  float mxa = fmaxf(a0, a1);
  float e0 = __expf(a0 - mxa), e1 = __expf(a1 - mxa);
  float wh0 = e0 / (e0 + e1), wh1 = e1 / (e0 + e1);
  float4 acc4 = make_float4(0.f, 0.f, 0.f, 0.f);
  for (int hop = 0; hop < 2; ++hop) {
    const unsigned long long* cm = hop ? colbits2T : colbitsT;
    if (t < 64) {
      unsigned long long word = (lane < kWords) ? cm[(size_t)lane * kN + d] : 0ull;
      if (lane == (d >> 6)) word |= 1ull << (d & 63);
      int cnt = __popcll(word);
      int inc = cnt;
      for (int o = 1; o < 64; o <<= 1) { int v = __shfl_up(inc, o); if (lane >= o) inc += v; }
      if (lane == 63) s_total = inc;
      int off = inc - cnt;
      int base = lane * 64;
      while (word) {
        int b = __builtin_ctzll(word);
        word &= word - 1;
        slist[off++] = (unsigned short)(base + b);
      }
    }
    __syncthreads();
    int total = s_total;
    float sd = sdst[((size_t)hop * kN + d) * 4 + h];
    const float4* hx4 = reinterpret_cast<const float4*>(hx + (size_t)hop * kN * kC1);
    const float* ssp = ssrc + (size_t)hop * kN * 4;
    float m1 = -3.0e38f, l1v = 0.f, m2 = -3.0e38f, l2v = 0.f;
    for (int q = lane; q < total; q += 64) {
      int s = slist[q];
      float mv = motif[(size_t)s * kN + d];
      float v = ssp[s * 4 + h] + sd;
      onl(m1, l1v, leakyf(v));
      onl(m2, l2v, leakyf(v * mv));
    }
#pragma unroll
    for (int o = 1; o < 64; o <<= 1) {
      float mm = __shfl_xor(m1, o), ll = __shfl_xor(l1v, o);
      mergeml(m1, l1v, mm, ll);
      float mm2 = __shfl_xor(m2, o), ll2 = __shfl_xor(l2v, o);
      mergeml(m2, l2v, mm2, ll2);
    }
    float il1 = 1.f / l1v, il2 = 1.f / l2v;
    float wh = hop ? wh1 : wh0;
    for (int c0 = 0; c0 < total; c0 += 64) {
      int nsi = min(64, total - c0);
      if (lane < nsi) {
        int s = slist[c0 + lane];
        float mv = motif[(size_t)s * kN + d];
        float v = ssp[s * 4 + h] + sd;
        w_lds[lane * 4 + h] = (0.5f * __expf(leakyf(v) - m1) * il1 +
                               0.5f * __expf(leakyf(v * mv) - m2) * il2) * wh;
      }
      __syncthreads();
      int q = h;
      for (; q + 4 < nsi; q += 8) {
        int s0 = slist[c0 + q], s1 = slist[c0 + q + 4];
        float4 r0 = hx4[(size_t)s0 * 64 + cq];
        float4 r1 = hx4[(size_t)s1 * 64 + cq];
        float w0 = w_lds[q * 4 + hq], w1 = w_lds[(q + 4) * 4 + hq];
        acc4.x += w0 * r0.x + w1 * r1.x;
        acc4.y += w0 * r0.y + w1 * r1.y;
        acc4.z += w0 * r0.z + w1 * r1.z;
        acc4.w += w0 * r0.w + w1 * r1.w;
      }
      if (q < nsi) {
        int s0 = slist[c0 + q];
        float4 r0 = hx4[(size_t)s0 * 64 + cq];
        float w0 = w_lds[q * 4 + hq];
        acc4.x += w0 * r0.x; acc4.y += w0 * r0.y;
        acc4.z += w0 * r0.z; acc4.w += w0 * r0.w;
      }
      __syncthreads();
    }
    __syncthreads();
  }
  red4[h][cq] = acc4;
  __syncthreads();
  if (t < 64) {
    float4 a = red4[0][t], b = red4[1][t], c = red4[2][t], e = red4[3][t];
    float4 bv = reinterpret_cast<const float4*>(bias)[t];
    float4 v;
    v.x = a.x + b.x + c.x + e.x + bv.x;
    v.y = a.y + b.y + c.y + e.y + bv.y;
    v.z = a.z + b.z + c.z + e.z + bv.z;
    v.w = a.w + b.w + c.w + e.w + bv.w;
    v.x = v.x > 0.f ? v.x : __expf(v.x) - 1.f;
    v.y = v.y > 0.f ? v.y : __expf(v.y) - 1.f;
    v.z = v.z > 0.f ? v.z : __expf(v.z) - 1.f;
    v.w = v.w > 0.f ? v.w : __expf(v.w) - 1.f;
    reinterpret_cast<float4*>(hbuf)[(size_t)d * 64 + t] = v;
  }
}

// layer-2 aggregation, fused stats; float4 FMA layout (16 s-slots x 16 quads);
// fused residual + LayerNorm + bias -> output. grid = N.
__global__ __launch_bounds__(256) void agg_l2(
    const float* __restrict__ hx,      // [2][N][64]
    const float* __restrict__ ssrc,    // [2][N]
    const float* __restrict__ sdst,    // [2][N]
    const float* __restrict__ motif,
    const unsigned long long* __restrict__ colbitsT,
    const unsigned long long* __restrict__ colbits2T,
    const float* __restrict__ hop_att,
    const float* __restrict__ res,     // [N][64]
    const float* __restrict__ lns, const float* __restrict__ lnb,
    const float* __restrict__ l2b,
    float* __restrict__ out) {
  int d = blockIdx.x;
  int t = threadIdx.x;
  int lane = t & 63;
  int g = t >> 6;      // wave id (stats)
  int cq = t & 15;     // channel quad [0,16)
  int sg = t >> 4;     // s-slot [0,16)
  __shared__ unsigned short slist[kN];
  __shared__ float w_lds[64];
  __shared__ int s_total;
  __shared__ float4 red4[16][16];
  __shared__ float out_lds[64];
  __shared__ float smst[4][4];
  float a0 = hop_att[0], a1 = hop_att[1];
  float mxa = fmaxf(a0, a1);
  float e0 = __expf(a0 - mxa), e1 = __expf(a1 - mxa);
  float wh0 = e0 / (e0 + e1), wh1 = e1 / (e0 + e1);
  float4 acc4 = make_float4(0.f, 0.f, 0.f, 0.f);
  for (int hop = 0; hop < 2; ++hop) {
    const unsigned long long* cm = hop ? colbits2T : colbitsT;
    if (t < 64) {
      unsigned long long word = (lane < kWords) ? cm[(size_t)lane * kN + d] : 0ull;
      if (lane == (d >> 6)) word |= 1ull << (d & 63);
      int cnt = __popcll(word);
      int inc = cnt;
      for (int o = 1; o < 64; o <<= 1) { int v = __shfl_up(inc, o); if (lane >= o) inc += v; }
      if (lane == 63) s_total = inc;
      int off = inc - cnt;
      int base = lane * 64;
      while (word) {
        int b = __builtin_ctzll(word);
        word &= word - 1;
        slist[off++] = (unsigned short)(base + b);
      }
    }
    __syncthreads();
    int total = s_total;
    float sd = sdst[(size_t)hop * kN + d];
    const float4* hx4 = reinterpret_cast<const float4*>(hx + (size_t)hop * kN * kC2);
    const float* ssp = ssrc + (size_t)hop * kN;
    float m1 = -3.0e38f, l1v = 0.f, m2 = -3.0e38f, l2v = 0.f;
    for (int q = t; q < total; q += 256) {
      int s = slist[q];
      float mv = motif[(size_t)s * kN + d];
      float v = ssp[s] + sd;
      onl(m1, l1v, leakyf(v));
      onl(m2, l2v, leakyf(v * mv));
    }
#pragma unroll
    for (int o = 1; o < 64; o <<= 1) {
      float mm = __shfl_xor(m1, o), ll = __shfl_xor(l1v, o);
      mergeml(m1, l1v, mm, ll);
      float mm2 = __shfl_xor(m2, o), ll2 = __shfl_xor(l2v, o);
      mergeml(m2, l2v, mm2, ll2);
    }
    if (lane == 0) {
      smst[g][0] = m1; smst[g][1] = l1v; smst[g][2] = m2; smst[g][3] = l2v;
    }
    __syncthreads();
    float M1 = -3.0e38f, L1 = 0.f, M2 = -3.0e38f, L2 = 0.f;
#pragma unroll
    for (int gg = 0; gg < 4; ++gg) {
      mergeml(M1, L1, smst[gg][0], smst[gg][1]);
      mergeml(M2, L2, smst[gg][2], smst[gg][3]);
    }
    float il1 = 1.f / L1, il2 = 1.f / L2;
    float wh = hop ? wh1 : wh0;
    for (int c0 = 0; c0 < total; c0 += 64) {
      int nsi = min(64, total - c0);
      if (t < nsi) {
        int s = slist[c0 + t];
        float mv = motif[(size_t)s * kN + d];
        float v = ssp[s] + sd;
        w_lds[t] = (0.5f * __expf(leakyf(v) - M1) * il1 +
                    0.5f * __expf(leakyf(v * mv) - M2) * il2) * wh;
      }
      __syncthreads();
      int q = sg;
      for (; q + 16 < nsi; q += 32) {
        int s0 = slist[c0 + q], s1 = slist[c0 + q + 16];
        float4 r0 = hx4[(size_t)s0 * 16 + cq];
        float4 r1 = hx4[(size_t)s1 * 16 + cq];
        float w0 = w_lds[q], w1 = w_lds[q + 16];
        acc4.x += w0 * r0.x + w1 * r1.x;
        acc4.y += w0 * r0.y + w1 * r1.y;
        acc4.z += w0 * r0.z + w1 * r1.z;
        acc4.w += w0 * r0.w + w1 * r1.w;
      }
      if (q < nsi) {
        int s0 = slist[c0 + q];
        float4 r0 = hx4[(size_t)s0 * 16 + cq];
        float w0 = w_lds[q];
        acc4.x += w0 * r0.x; acc4.y += w0 * r0.y;
        acc4.z += w0 * r0.z; acc4.w += w0 * r0.w;
      }
      __syncthreads();
    }
    __syncthreads();
  }
  red4[sg][cq] = acc4;
  __syncthreads();
  if (t < 16) {
    float4 v = make_float4(0.f, 0.f, 0.f, 0.f);
#pragma unroll
    for (int q = 0; q < 16; ++q) {
      float4 a = red4[q][t];
      v.x += a.x; v.y += a.y; v.z += a.z; v.w += a.w;
    }
    out_lds[t * 4 + 0] = v.x;
    out_lds[t * 4 + 1] = v.y;
    out_lds[t * 4 + 2] = v.z;
    out_lds[t * 4 + 3] = v.w;
  }
  __syncthreads();
  if (t < 64) {
    float v = out_lds[t] + res[(size_t)d * kC2 + t];
    float s = v;
    for (int o = 32; o; o >>= 1) s += __shfl_xor(s, o);
    float mu = s * (1.f / kC2);
    float dv = v - mu;
    float q = dv * dv;
    for (int o = 32; o; o >>= 1) q += __shfl_xor(q, o);
    float var = q * (1.f / kC2);
    out[(size_t)d * kC2 + t] = dv * rsqrtf(var + kLnEps) * lns[t] + lnb[t] + l2b[t];
  }
}

}  // namespace

extern "C" void kernel_launch(void* const* d_in, const int* in_sizes, int n_in,
                              void* d_out, int out_size, void* d_ws, size_t ws_size,
                              hipStream_t stream) {
  const float* x    = (const float*)d_in[0];
  const int*   ei   = (const int*)d_in[1];
  const float* l1w  = (const float*)d_in[2];
  const float* l1as = (const float*)d_in[3];
  const float* l1ad = (const float*)d_in[4];
  const float* l1ha = (const float*)d_in[5];
  const float* l1b  = (const float*)d_in[6];
  const float* l2w  = (const float*)d_in[7];
  const float* l2as = (const float*)d_in[8];
  const float* l2ad = (const float*)d_in[9];
  const float* l2ha = (const float*)d_in[10];
  const float* l2rw = (const float*)d_in[11];
  const float* lns  = (const float*)d_in[12];
  const float* lnb  = (const float*)d_in[13];
  const float* l2b  = (const float*)d_in[14];
  int E = in_sizes[1] / 2;

  // ---- workspace layout (bytes) ----
  size_t o = 0;
  auto take = [&](size_t bytes) { size_t r = o; o += (bytes + 255) & ~(size_t)255; return r; };
  size_t oRB  = take((size_t)kN * kWords * 8);      // rowbits (zeroed)
  size_t oCB  = take((size_t)kWords * kN * 8);      // colbitsT (zeroed)
  size_t zEnd = o;                                  // zero region end
  size_t oCB2 = take((size_t)kWords * kN * 8);      // colbits2T (fully written)
  size_t oA2  = take((size_t)kN * kN * 2);          // dense A2 u16
  size_t oMF  = take((size_t)kN * kN * 4);
  size_t oHX1 = take((size_t)2 * kN * kC1 * 4);
  size_t oH   = take((size_t)kN * kC1 * 4);
  size_t oHX2 = take((size_t)3 * kN * kC2 * 4);     // hop0 | hop1 | res
  size_t oSS1 = take((size_t)2 * kN * 4 * 4);
  size_t oSD1 = take((size_t)2 * kN * 4 * 4);
  size_t oSS2 = take((size_t)2 * kN * 4);
  size_t oSD2 = take((size_t)2 * kN * 4);
  if (ws_size < o) return;  // insufficient scratch; fail visibly

  char* w = (char*)d_ws;
  unsigned long long* rowbits = (unsigned long long*)(w + oRB);
  unsigned long long* colbitsT = (unsigned long long*)(w + oCB);
  unsigned long long* colbits2T = (unsigned long long*)(w + oCB2);
  unsigned short* A2 = (unsigned short*)(w + oA2);
  float* motif = (float*)(w + oMF);
  float* hx1 = (float*)(w + oHX1);
  float* hbuf = (float*)(w + oH);
  float* hx2 = (float*)(w + oHX2);
  float* res = hx2 + (size_t)2 * kN * kC2;
  float* ss1 = (float*)(w + oSS1);
  float* sd1 = (float*)(w + oSD1);
  float* ss2 = (float*)(w + oSS2);
  float* sd2 = (float*)(w + oSD2);

  hipMemsetAsync(d_ws, 0, zEnd, stream);

  build_bits<<<(E + 255) / 256, 256, 0, stream>>>(ei, E, rowbits, colbitsT);
  a2_tiled<<<dim3(kN / 64, kN / 64), 256, 0, stream>>>(rowbits, colbitsT, A2, colbits2T);
  a3_dense<<<kN, 256, 0, stream>>>(rowbits, A2, motif);

  gemm1<<<dim3(kC1 / 64, kN / 64, 2), 256, 0, stream>>>(x, l1w, hx1, l1as, l1ad, ss1, sd1);
  agg_l1<<<kN, 256, 0, stream>>>(hx1, ss1, sd1, motif, colbitsT, colbits2T,
                                 l1ha, l1b, hbuf);

  gemm2<<<dim3(1, kN / 64, 3), 256, 0, stream>>>(hbuf, l2w, l2rw, hx2,
                                                 l2as, l2ad, ss2, sd2);
  agg_l2<<<kN, 256, 0, stream>>>(hx2, ss2, sd2, motif, colbitsT, colbits2T,
                                 l2ha, res, lns, lnb, l2b, (float*)d_out);
}

// Round 12
// 173.698 us; speedup vs baseline: 1.3944x; 1.0844x over previous
//
#include <hip/hip_runtime.h>

namespace {

constexpr int kN = 2048;
constexpr int kWords = kN / 64;   // 32
constexpr int kC1 = 256;          // HEADS*HID
constexpr int kC2 = 64;           // OUT_CH
constexpr int kIN = 512;
constexpr float kNegSlope = 0.2f;
constexpr float kLnEps = 1e-5f;

__device__ __forceinline__ float leakyf(float v) {
  return v >= 0.f ? v : kNegSlope * v;
}
__device__ __forceinline__ void onl(float& m, float& l, float v) {
  if (v > m) { l = l * __expf(m - v) + 1.f; m = v; }
  else       { l += __expf(v - m); }
}
__device__ __forceinline__ void mergeml(float& M, float& L, float m, float l) {
  if (m > M) { L = L * __expf(M - m) + l; M = m; }
  else       { L += l * __expf(m - M); }
}

// ---------------- adjacency bitsets ----------------
__global__ void build_bits(const int* __restrict__ ei, int E,
                           unsigned long long* rowbits, unsigned long long* colbitsT) {
  int e = blockIdx.x * 256 + threadIdx.x;
  if (e >= E) return;
  int s = ei[e], d = ei[E + e];
  atomicOr(&rowbits[(size_t)s * kWords + (d >> 6)], 1ull << (d & 63));
  atomicOr(&colbitsT[(size_t)(s >> 6) * kN + d], 1ull << (s & 63));
}

// Tiled popcount-GEMM: A2[s][d] = popc(row_s & col_d) for a 64x64 tile.
// Also emits colbits2T structure words (tile exclusively owns them).
__global__ __launch_bounds__(256) void a2_tiled(
    const unsigned long long* __restrict__ rowbits,
    const unsigned long long* __restrict__ colbitsT,
    unsigned short* __restrict__ A2,
    unsigned long long* __restrict__ colbits2T) {
  int bx = blockIdx.x, by = blockIdx.y;   // d-tile, s-tile
  int t = threadIdx.x;
  __shared__ unsigned long long rb[64][33];  // padded: conflict-free
  __shared__ unsigned long long cb[32][64];
  __shared__ unsigned long long cw[64];
  int s0 = by * 64, d0 = bx * 64;
  for (int i = t; i < 64 * 32; i += 256) {
    int ss = i >> 5, w = i & 31;
    rb[ss][w] = rowbits[(size_t)(s0 + ss) * kWords + w];
  }
  for (int i = t; i < 32 * 64; i += 256) {
    int w = i >> 6, dd = i & 63;
    cb[w][dd] = colbitsT[(size_t)w * kN + d0 + dd];
  }
  if (t < 64) cw[t] = 0ull;
  __syncthreads();
  int tx = t & 15, ty4 = (t >> 4) * 4;
  int acc[4][4] = {};
#pragma unroll 4
  for (int w = 0; w < 32; ++w) {
    unsigned long long r0 = rb[ty4 + 0][w], r1 = rb[ty4 + 1][w];
    unsigned long long r2 = rb[ty4 + 2][w], r3 = rb[ty4 + 3][w];
    unsigned long long c0 = cb[w][tx], c1 = cb[w][tx + 16];
    unsigned long long c2 = cb[w][tx + 32], c3 = cb[w][tx + 48];
    acc[0][0] += __popcll(r0 & c0); acc[0][1] += __popcll(r0 & c1);
    acc[0][2] += __popcll(r0 & c2); acc[0][3] += __popcll(r0 & c3);
    acc[1][0] += __popcll(r1 & c0); acc[1][1] += __popcll(r1 & c1);
    acc[1][2] += __popcll(r1 & c2); acc[1][3] += __popcll(r1 & c3);
    acc[2][0] += __popcll(r2 & c0); acc[2][1] += __popcll(r2 & c1);
    acc[2][2] += __popcll(r2 & c2); acc[2][3] += __popcll(r2 & c3);
    acc[3][0] += __popcll(r3 & c0); acc[3][1] += __popcll(r3 & c1);
    acc[3][2] += __popcll(r3 & c2); acc[3][3] += __popcll(r3 & c3);
  }
#pragma unroll
  for (int i = 0; i < 4; ++i)
#pragma unroll
    for (int j = 0; j < 4; ++j)
      A2[(size_t)(s0 + ty4 + i) * kN + d0 + tx + 16 * j] = (unsigned short)acc[i][j];
#pragma unroll
  for (int j = 0; j < 4; ++j) {
    unsigned long long m = 0;
#pragma unroll
    for (int i = 0; i < 4; ++i)
      if (acc[i][j]) m |= 1ull << (ty4 + i);
    if (m) atomicOr(&cw[tx + 16 * j], m);
  }
  __syncthreads();
  if (t < 64) colbits2T[(size_t)by * kN + d0 + t] = cw[t];
}

// A3 row s = sum_{j in rowA[s]} A2[j,:]: dense coalesced uint4 packed-u16
// adds. Writes unnormalized u16 A3 + 1/rowsum. One block per s.
// Thread t owns uint4 #t of the row = d in [8t, 8t+8).
__global__ __launch_bounds__(256) void a3_dense(
    const unsigned long long* __restrict__ rowbits,
    const unsigned short* __restrict__ A2,
    unsigned short* __restrict__ a3u,
    float* __restrict__ invr) {
  int s = blockIdx.x;
  int t = threadIdx.x;
  int lane = t & 63;
  __shared__ unsigned short jl[kN];
  __shared__ int jtot_s;
  __shared__ float redv[4];
  if (t < 64) {
    unsigned long long word = (lane < kWords) ? rowbits[(size_t)s * kWords + lane] : 0ull;
    int c = __popcll(word);
    int inc = c;
    for (int o = 1; o < 64; o <<= 1) { int v = __shfl_up(inc, o); if (lane >= o) inc += v; }
    if (lane == 63) jtot_s = inc;
    int off = inc - c;
    int base = lane * 64;
    while (word) {
      int b = __builtin_ctzll(word);
      word &= word - 1;
      jl[off++] = (unsigned short)(base + b);
    }
  }
  __syncthreads();
  int jtot = jtot_s;
  const uint4* a2v = reinterpret_cast<const uint4*>(A2);  // 256 uint4 per row
  uint4 acc = make_uint4(0u, 0u, 0u, 0u);
  int ji = 0;
  for (; ji + 4 <= jtot; ji += 4) {
    uint4 v0 = a2v[(size_t)jl[ji + 0] * 256 + t];
    uint4 v1 = a2v[(size_t)jl[ji + 1] * 256 + t];
    uint4 v2 = a2v[(size_t)jl[ji + 2] * 256 + t];
    uint4 v3 = a2v[(size_t)jl[ji + 3] * 256 + t];
    acc.x += v0.x + v1.x + v2.x + v3.x;
    acc.y += v0.y + v1.y + v2.y + v3.y;
    acc.z += v0.z + v1.z + v2.z + v3.z;
    acc.w += v0.w + v1.w + v2.w + v3.w;
  }
  for (; ji < jtot; ++ji) {
    uint4 v = a2v[(size_t)jl[ji] * 256 + t];
    acc.x += v.x; acc.y += v.y; acc.z += v.z; acc.w += v.w;
  }
  reinterpret_cast<uint4*>(a3u)[(size_t)s * 256 + t] = acc;
  float tot = (float)((acc.x & 0xffffu) + (acc.x >> 16) +
                      (acc.y & 0xffffu) + (acc.y >> 16) +
                      (acc.z & 0xffffu) + (acc.z >> 16) +
                      (acc.w & 0xffffu) + (acc.w >> 16));
  for (int o = 32; o; o >>= 1) tot += __shfl_xor(tot, o);
  if (lane == 0) redv[t >> 6] = tot;
  __syncthreads();
  if (t == 0)
    invr[s] = 1.f / fmaxf(redv[0] + redv[1] + redv[2] + redv[3], 1.f);
}

// motifT[d][s] = a3u[s][d] * invr[s]  (LDS-tiled transpose + normalize)
__global__ __launch_bounds__(256) void transpose_motif(
    const unsigned short* __restrict__ a3u, const float* __restrict__ invr,
    float* __restrict__ motifT) {
  __shared__ float tile[64][65];
  __shared__ float invs[64];
  int d0 = blockIdx.x * 64, s0 = blockIdx.y * 64;
  int t = threadIdx.x;
  int tx = t & 63, ty = t >> 6;
  if (t < 64) invs[t] = invr[s0 + t];
  __syncthreads();
#pragma unroll
  for (int i = 0; i < 64; i += 4)
    tile[ty + i][tx] = (float)a3u[(size_t)(s0 + ty + i) * kN + d0 + tx] * invs[ty + i];
  __syncthreads();
#pragma unroll
  for (int i = 0; i < 64; i += 4)
    motifT[(size_t)(d0 + ty + i) * kN + s0 + tx] = tile[tx][ty + i];
}

// layer-1 GEMM with fused s_src/s_dst epilogue. grid (4, 32, 2)
__global__ __launch_bounds__(256) void gemm1(
    const float* __restrict__ x, const float* __restrict__ l1w,
    float* __restrict__ hx1,
    const float* __restrict__ l1as, const float* __restrict__ l1ad,
    float* __restrict__ ss1, float* __restrict__ sd1) {
  int hop = blockIdx.z;
  int row0 = blockIdx.y * 64, col0 = blockIdx.x * 64;
  const float* B = l1w + (size_t)hop * kIN * kC1;
  float* Cz = hx1 + (size_t)hop * kN * kC1;
  __shared__ float As[16][65];
  __shared__ float Bs[16][65];
  int t = threadIdx.x;
  int tx = t & 15, ty = t >> 4;
  float acc[4][4] = {};
  for (int k0 = 0; k0 < kIN; k0 += 16) {
    {
      int e = t * 4;
      int m = e >> 4, kk = e & 15;
      float4 va = *reinterpret_cast<const float4*>(x + (size_t)(row0 + m) * kIN + k0 + kk);
      As[kk + 0][m] = va.x; As[kk + 1][m] = va.y;
      As[kk + 2][m] = va.z; As[kk + 3][m] = va.w;
    }
    {
      int kb = t >> 4, nb = (t & 15) * 4;
      float4 vb = *reinterpret_cast<const float4*>(B + (size_t)(k0 + kb) * kC1 + col0 + nb);
      Bs[kb][nb + 0] = vb.x; Bs[kb][nb + 1] = vb.y;
      Bs[kb][nb + 2] = vb.z; Bs[kb][nb + 3] = vb.w;
    }
    __syncthreads();
#pragma unroll
    for (int kk2 = 0; kk2 < 16; ++kk2) {
      float a[4], b[4];
#pragma unroll
      for (int i = 0; i < 4; ++i) a[i] = As[kk2][ty * 4 + i];
#pragma unroll
      for (int j = 0; j < 4; ++j) b[j] = Bs[kk2][tx * 4 + j];
#pragma unroll
      for (int i = 0; i < 4; ++i)
#pragma unroll
        for (int j = 0; j < 4; ++j) acc[i][j] += a[i] * b[j];
    }
    __syncthreads();
  }
#pragma unroll
  for (int i = 0; i < 4; ++i)
#pragma unroll
    for (int j = 0; j < 4; ++j)
      Cz[(size_t)(row0 + ty * 4 + i) * kC1 + col0 + tx * 4 + j] = acc[i][j];
  int h = col0 >> 6;
  float as_[4], ad_[4];
#pragma unroll
  for (int j = 0; j < 4; ++j) {
    as_[j] = l1as[hop * kC1 + col0 + tx * 4 + j];
    ad_[j] = l1ad[hop * kC1 + col0 + tx * 4 + j];
  }
#pragma unroll
  for (int i = 0; i < 4; ++i) {
    float ps = acc[i][0] * as_[0] + acc[i][1] * as_[1] +
               acc[i][2] * as_[2] + acc[i][3] * as_[3];
    float pd = acc[i][0] * ad_[0] + acc[i][1] * ad_[1] +
               acc[i][2] * ad_[2] + acc[i][3] * ad_[3];
#pragma unroll
    for (int o = 1; o < 16; o <<= 1) {
      ps += __shfl_xor(ps, o);
      pd += __shfl_xor(pd, o);
    }
    if (tx == 0) {
      int n = row0 + ty * 4 + i;
      ss1[((size_t)hop * kN + n) * 4 + h] = ps;
      sd1[((size_t)hop * kN + n) * 4 + h] = pd;
    }
  }
}

// layer-2 GEMM (z: 0,1 = hops via l2w with src/dst epilogue; 2 = res via l2rw)
__global__ __launch_bounds__(256) void gemm2(
    const float* __restrict__ A, const float* __restrict__ l2w,
    const float* __restrict__ l2rw, float* __restrict__ C,
    const float* __restrict__ attS, const float* __restrict__ attD,
    float* __restrict__ ssO, float* __restrict__ sdO) {
  int z = blockIdx.z;
  const float* B = (z < 2) ? l2w + (size_t)z * kC1 * kC2 : l2rw;
  float* Cz = C + (size_t)z * kN * kC2;
  __shared__ float As[16][65];
  __shared__ float Bs[16][65];
  int t = threadIdx.x;
  int tx = t & 15, ty = t >> 4;
  int row0 = blockIdx.y * 64;
  float acc[4][4] = {};
  for (int k0 = 0; k0 < kC1; k0 += 16) {
    {
      int e = t * 4;
      int m = e >> 4, kk = e & 15;
      float4 va = *reinterpret_cast<const float4*>(A + (size_t)(row0 + m) * kC1 + k0 + kk);
      As[kk + 0][m] = va.x; As[kk + 1][m] = va.y;
      As[kk + 2][m] = va.z; As[kk + 3][m] = va.w;
    }
    {
      int kb = t >> 4, nb = (t & 15) * 4;
      float4 vb = *reinterpret_cast<const float4*>(B + (size_t)(k0 + kb) * kC2 + nb);
      Bs[kb][nb + 0] = vb.x; Bs[kb][nb + 1] = vb.y;
      Bs[kb][nb + 2] = vb.z; Bs[kb][nb + 3] = vb.w;
    }
    __syncthreads();
#pragma unroll
    for (int kk2 = 0; kk2 < 16; ++kk2) {
      float a[4], b[4];
#pragma unroll
      for (int i = 0; i < 4; ++i) a[i] = As[kk2][ty * 4 + i];
#pragma unroll
      for (int j = 0; j < 4; ++j) b[j] = Bs[kk2][tx * 4 + j];
#pragma unroll
      for (int i = 0; i < 4; ++i)
#pragma unroll
        for (int j = 0; j < 4; ++j) acc[i][j] += a[i] * b[j];
    }
    __syncthreads();
  }
#pragma unroll
  for (int i = 0; i < 4; ++i)
#pragma unroll
    for (int j = 0; j < 4; ++j)
      Cz[(size_t)(row0 + ty * 4 + i) * kC2 + tx * 4 + j] = acc[i][j];
  if (z < 2) {
    float as_[4], ad_[4];
#pragma unroll
    for (int j = 0; j < 4; ++j) {
      as_[j] = attS[z * kC2 + tx * 4 + j];
      ad_[j] = attD[z * kC2 + tx * 4 + j];
    }
#pragma unroll
    for (int i = 0; i < 4; ++i) {
      float ps = acc[i][0] * as_[0] + acc[i][1] * as_[1] +
                 acc[i][2] * as_[2] + acc[i][3] * as_[3];
      float pd = acc[i][0] * ad_[0] + acc[i][1] * ad_[1] +
                 acc[i][2] * ad_[2] + acc[i][3] * ad_[3];
#pragma unroll
      for (int o = 1; o < 16; o <<= 1) {
        ps += __shfl_xor(ps, o);
        pd += __shfl_xor(pd, o);
      }
      if (tx == 0) {
        int n = row0 + ty * 4 + i;
        ssO[(size_t)z * kN + n] = ps;
        sdO[(size_t)z * kN + n] = pd;
      }
    }
  }
}

// layer-1 aggregation, fused stats; motifT row staged in LDS.
__global__ __launch_bounds__(256) void agg_l1(
    const float* __restrict__ hx,      // [2][N][256]
    const float* __restrict__ ssrc,    // [2][N][4]
    const float* __restrict__ sdst,    // [2][N][4]
    const float* __restrict__ motifT,  // [N(d)][N(s)]
    const unsigned long long* __restrict__ colbitsT,
    const unsigned long long* __restrict__ colbits2T,
    const float* __restrict__ hop_att,
    const float* __restrict__ bias,
    float* __restrict__ hbuf) {
  int d = blockIdx.x;
  int t = threadIdx.x;
  int lane = t & 63;
  int h = t >> 6;       // stats wave == head; also s-slot for FMA
  int cq = lane;        // channel quad [0,64)
  int hq = cq >> 4;     // head of this quad
  __shared__ unsigned short slist[kN];
  __shared__ float mrow[kN];
  __shared__ float w_lds[64 * 4];
  __shared__ int s_total;
  __shared__ float4 red4[4][64];
  {
    const float4* mp = reinterpret_cast<const float4*>(motifT + (size_t)d * kN);
    float4* mr = reinterpret_cast<float4*>(mrow);
    mr[t] = mp[t];
    mr[t + 256] = mp[t + 256];
  }
  float a0 = hop_att[0], a1 = hop_att[1];
  float mxa = fmaxf(a0, a1);
  float e0 = __expf(a0 - mxa), e1 = __expf(a1 - mxa);
  float wh0 = e0 / (e0 + e1), wh1 = e1 / (e0 + e1);
  float4 acc4 = make_float4(0.f, 0.f, 0.f, 0.f);
  for (int hop = 0; hop < 2; ++hop) {
    const unsigned long long* cm = hop ? colbits2T : colbitsT;
    if (t < 64) {
      unsigned long long word = (lane < kWords) ? cm[(size_t)lane * kN + d] : 0ull;
      if (lane == (d >> 6)) word |= 1ull << (d & 63);
      int cnt = __popcll(word);
      int inc = cnt;
      for (int o = 1; o < 64; o <<= 1) { int v = __shfl_up(inc, o); if (lane >= o) inc += v; }
      if (lane == 63) s_total = inc;
      int off = inc - cnt;
      int base = lane * 64;
      while (word) {
        int b = __builtin_ctzll(word);
        word &= word - 1;
        slist[off++] = (unsigned short)(base + b);
      }
    }
    __syncthreads();
    int total = s_total;
    float sd = sdst[((size_t)hop * kN + d) * 4 + h];
    const float4* hx4 = reinterpret_cast<const float4*>(hx + (size_t)hop * kN * kC1);
    const float* ssp = ssrc + (size_t)hop * kN * 4;
    float m1 = -3.0e38f, l1v = 0.f, m2 = -3.0e38f, l2v = 0.f;
    for (int q = lane; q < total; q += 64) {
      int s = slist[q];
      float mv = mrow[s];
      float v = ssp[s * 4 + h] + sd;
      onl(m1, l1v, leakyf(v));
      onl(m2, l2v, leakyf(v * mv));
    }
#pragma unroll
    for (int o = 1; o < 64; o <<= 1) {
      float mm = __shfl_xor(m1, o), ll = __shfl_xor(l1v, o);
      mergeml(m1, l1v, mm, ll);
      float mm2 = __shfl_xor(m2, o), ll2 = __shfl_xor(l2v, o);
      mergeml(m2, l2v, mm2, ll2);
    }
    float il1 = 1.f / l1v, il2 = 1.f / l2v;
    float wh = hop ? wh1 : wh0;
    for (int c0 = 0; c0 < total; c0 += 64) {
      int nsi = min(64, total - c0);
      if (lane < nsi) {
        int s = slist[c0 + lane];
        float mv = mrow[s];
        float v = ssp[s * 4 + h] + sd;
        w_lds[lane * 4 + h] = (0.5f * __expf(leakyf(v) - m1) * il1 +
                               0.5f * __expf(leakyf(v * mv) - m2) * il2) * wh;
      }
      __syncthreads();
      int q = h;
      for (; q + 4 < nsi; q += 8) {
        int s0 = slist[c0 + q], s1 = slist[c0 + q + 4];
        float4 r0 = hx4[(size_t)s0 * 64 + cq];
        float4 r1 = hx4[(size_t)s1 * 64 + cq];
        float w0 = w_lds[q * 4 + hq], w1 = w_lds[(q + 4) * 4 + hq];
        acc4.x += w0 * r0.x + w1 * r1.x;
        acc4.y += w0 * r0.y + w1 * r1.y;
        acc4.z += w0 * r0.z + w1 * r1.z;
        acc4.w += w0 * r0.w + w1 * r1.w;
      }
      if (q < nsi) {
        int s0 = slist[c0 + q];
        float4 r0 = hx4[(size_t)s0 * 64 + cq];
        float w0 = w_lds[q * 4 + hq];
        acc4.x += w0 * r0.x; acc4.y += w0 * r0.y;
        acc4.z += w0 * r0.z; acc4.w += w0 * r0.w;
      }
      __syncthreads();
    }
    __syncthreads();
  }
  red4[h][cq] = acc4;
  __syncthreads();
  if (t < 64) {
    float4 a = red4[0][t], b = red4[1][t], c = red4[2][t], e = red4[3][t];
    float4 bv = reinterpret_cast<const float4*>(bias)[t];
    float4 v;
    v.x = a.x + b.x + c.x + e.x + bv.x;
    v.y = a.y + b.y + c.y + e.y + bv.y;
    v.z = a.z + b.z + c.z + e.z + bv.z;
    v.w = a.w + b.w + c.w + e.w + bv.w;
    v.x = v.x > 0.f ? v.x : __expf(v.x) - 1.f;
    v.y = v.y > 0.f ? v.y : __expf(v.y) - 1.f;
    v.z = v.z > 0.f ? v.z : __expf(v.z) - 1.f;
    v.w = v.w > 0.f ? v.w : __expf(v.w) - 1.f;
    reinterpret_cast<float4*>(hbuf)[(size_t)d * 64 + t] = v;
  }
}

// layer-2 aggregation, fused stats; motifT row staged in LDS;
// fused residual + LayerNorm + bias -> output. grid = N.
__global__ __launch_bounds__(256) void agg_l2(
    const float* __restrict__ hx,      // [2][N][64]
    const float* __restrict__ ssrc,    // [2][N]
    const float* __restrict__ sdst,    // [2][N]
    const float* __restrict__ motifT,
    const unsigned long long* __restrict__ colbitsT,
    const unsigned long long* __restrict__ colbits2T,
    const float* __restrict__ hop_att,
    const float* __restrict__ res,     // [N][64]
    const float* __restrict__ lns, const float* __restrict__ lnb,
    const float* __restrict__ l2b,
    float* __restrict__ out) {
  int d = blockIdx.x;
  int t = threadIdx.x;
  int lane = t & 63;
  int g = t >> 6;      // wave id (stats)
  int cq = t & 15;     // channel quad [0,16)
  int sg = t >> 4;     // s-slot [0,16)
  __shared__ unsigned short slist[kN];
  __shared__ float mrow[kN];
  __shared__ float w_lds[64];
  __shared__ int s_total;
  __shared__ float4 red4[16][16];
  __shared__ float out_lds[64];
  __shared__ float smst[4][4];
  {
    const float4* mp = reinterpret_cast<const float4*>(motifT + (size_t)d * kN);
    float4* mr = reinterpret_cast<float4*>(mrow);
    mr[t] = mp[t];
    mr[t + 256] = mp[t + 256];
  }
  float a0 = hop_att[0], a1 = hop_att[1];
  float mxa = fmaxf(a0, a1);
  float e0 = __expf(a0 - mxa), e1 = __expf(a1 - mxa);
  float wh0 = e0 / (e0 + e1), wh1 = e1 / (e0 + e1);
  float4 acc4 = make_float4(0.f, 0.f, 0.f, 0.f);
  for (int hop = 0; hop < 2; ++hop) {
    const unsigned long long* cm = hop ? colbits2T : colbitsT;
    if (t < 64) {
      unsigned long long word = (lane < kWords) ? cm[(size_t)lane * kN + d] : 0ull;
      if (lane == (d >> 6)) word |= 1ull << (d & 63);
      int cnt = __popcll(word);
      int inc = cnt;
      for (int o = 1; o < 64; o <<= 1) { int v = __shfl_up(inc, o); if (lane >= o) inc += v; }
      if (lane == 63) s_total = inc;
      int off = inc - cnt;
      int base = lane * 64;
      while (word) {
        int b = __builtin_ctzll(word);
        word &= word - 1;
        slist[off++] = (unsigned short)(base + b);
      }
    }
    __syncthreads();
    int total = s_total;
    float sd = sdst[(size_t)hop * kN + d];
    const float4* hx4 = reinterpret_cast<const float4*>(hx + (size_t)hop * kN * kC2);
    const float* ssp = ssrc + (size_t)hop * kN;
    float m1 = -3.0e38f, l1v = 0.f, m2 = -3.0e38f, l2v = 0.f;
    for (int q = t; q < total; q += 256) {
      int s = slist[q];
      float mv = mrow[s];
      float v = ssp[s] + sd;
      onl(m1, l1v, leakyf(v));
      onl(m2, l2v, leakyf(v * mv));
    }
#pragma unroll
    for (int o = 1; o < 64; o <<= 1) {
      float mm = __shfl_xor(m1, o), ll = __shfl_xor(l1v, o);
      mergeml(m1, l1v, mm, ll);
      float mm2 = __shfl_xor(m2, o), ll2 = __shfl_xor(l2v, o);
      mergeml(m2, l2v, mm2, ll2);
    }
    if (lane == 0) {
      smst[g][0] = m1; smst[g][1] = l1v; smst[g][2] = m2; smst[g][3] = l2v;
    }
    __syncthreads();
    float M1 = -3.0e38f, L1 = 0.f, M2 = -3.0e38f, L2 = 0.f;
#pragma unroll
    for (int gg = 0; gg < 4; ++gg) {
      mergeml(M1, L1, smst[gg][0], smst[gg][1]);
      mergeml(M2, L2, smst[gg][2], smst[gg][3]);
    }
    float il1 = 1.f / L1, il2 = 1.f / L2;
    float wh = hop ? wh1 : wh0;
    for (int c0 = 0; c0 < total; c0 += 64) {
      int nsi = min(64, total - c0);
      if (t < nsi) {
        int s = slist[c0 + t];
        float mv = mrow[s];
        float v = ssp[s] + sd;
        w_lds[t] = (0.5f * __expf(leakyf(v) - M1) * il1 +
                    0.5f * __expf(leakyf(v * mv) - M2) * il2) * wh;
      }
      __syncthreads();
      int q = sg;
      for (; q + 16 < nsi; q += 32) {
        int s0 = slist[c0 + q], s1 = slist[c0 + q + 16];
        float4 r0 = hx4[(size_t)s0 * 16 + cq];
        float4 r1 = hx4[(size_t)s1 * 16 + cq];
        float w0 = w_lds[q], w1 = w_lds[q + 16];
        acc4.x += w0 * r0.x + w1 * r1.x;
        acc4.y += w0 * r0.y + w1 * r1.y;
        acc4.z += w0 * r0.z + w1 * r1.z;
        acc4.w += w0 * r0.w + w1 * r1.w;
      }
      if (q < nsi) {
        int s0 = slist[c0 + q];
        float4 r0 = hx4[(size_t)s0 * 16 + cq];
        float w0 = w_lds[q];
        acc4.x += w0 * r0.x; acc4.y += w0 * r0.y;
        acc4.z += w0 * r0.z; acc4.w += w0 * r0.w;
      }
      __syncthreads();
    }
    __syncthreads();
  }
  red4[sg][cq] = acc4;
  __syncthreads();
  if (t < 16) {
    float4 v = make_float4(0.f, 0.f, 0.f, 0.f);
#pragma unroll
    for (int q = 0; q < 16; ++q) {
      float4 a = red4[q][t];
      v.x += a.x; v.y += a.y; v.z += a.z; v.w += a.w;
    }
    out_lds[t * 4 + 0] = v.x;
    out_lds[t * 4 + 1] = v.y;
    out_lds[t * 4 + 2] = v.z;
    out_lds[t * 4 + 3] = v.w;
  }
  __syncthreads();
  if (t < 64) {
    float v = out_lds[t] + res[(size_t)d * kC2 + t];
    float s = v;
    for (int o = 32; o; o >>= 1) s += __shfl_xor(s, o);
    float mu = s * (1.f / kC2);
    float dv = v - mu;
    float q = dv * dv;
    for (int o = 32; o; o >>= 1) q += __shfl_xor(q, o);
    float var = q * (1.f / kC2);
    out[(size_t)d * kC2 + t] = dv * rsqrtf(var + kLnEps) * lns[t] + lnb[t] + l2b[t];
  }
}

}  // namespace

extern "C" void kernel_launch(void* const* d_in, const int* in_sizes, int n_in,
                              void* d_out, int out_size, void* d_ws, size_t ws_size,
                              hipStream_t stream) {
  const float* x    = (const float*)d_in[0];
  const int*   ei   = (const int*)d_in[1];
  const float* l1w  = (const float*)d_in[2];
  const float* l1as = (const float*)d_in[3];
  const float* l1ad = (const float*)d_in[4];
  const float* l1ha = (const float*)d_in[5];
  const float* l1b  = (const float*)d_in[6];
  const float* l2w  = (const float*)d_in[7];
  const float* l2as = (const float*)d_in[8];
  const float* l2ad = (const float*)d_in[9];
  const float* l2ha = (const float*)d_in[10];
  const float* l2rw = (const float*)d_in[11];
  const float* lns  = (const float*)d_in[12];
  const float* lnb  = (const float*)d_in[13];
  const float* l2b  = (const float*)d_in[14];
  int E = in_sizes[1] / 2;

  // ---- workspace layout (bytes) ----
  size_t o = 0;
  auto take = [&](size_t bytes) { size_t r = o; o += (bytes + 255) & ~(size_t)255; return r; };
  size_t oRB  = take((size_t)kN * kWords * 8);      // rowbits (zeroed)
  size_t oCB  = take((size_t)kWords * kN * 8);      // colbitsT (zeroed)
  size_t zEnd = o;                                  // zero region end
  size_t oCB2 = take((size_t)kWords * kN * 8);      // colbits2T (fully written)
  size_t oA2  = take((size_t)kN * kN * 2);          // dense A2 u16
  size_t oA3  = take((size_t)kN * kN * 2);          // dense A3 u16 (unnormalized)
  size_t oINV = take((size_t)kN * 4);               // 1/rowsum
  size_t oMFT = take((size_t)kN * kN * 4);          // motifT f32
  size_t oHX1 = take((size_t)2 * kN * kC1 * 4);
  size_t oH   = take((size_t)kN * kC1 * 4);
  size_t oHX2 = take((size_t)3 * kN * kC2 * 4);     // hop0 | hop1 | res
  size_t oSS1 = take((size_t)2 * kN * 4 * 4);
  size_t oSD1 = take((size_t)2 * kN * 4 * 4);
  size_t oSS2 = take((size_t)2 * kN * 4);
  size_t oSD2 = take((size_t)2 * kN * 4);
  if (ws_size < o) return;  // insufficient scratch; fail visibly

  char* w = (char*)d_ws;
  unsigned long long* rowbits = (unsigned long long*)(w + oRB);
  unsigned long long* colbitsT = (unsigned long long*)(w + oCB);
  unsigned long long* colbits2T = (unsigned long long*)(w + oCB2);
  unsigned short* A2 = (unsigned short*)(w + oA2);
  unsigned short* A3u = (unsigned short*)(w + oA3);
  float* invr = (float*)(w + oINV);
  float* motifT = (float*)(w + oMFT);
  float* hx1 = (float*)(w + oHX1);
  float* hbuf = (float*)(w + oH);
  float* hx2 = (float*)(w + oHX2);
  float* res = hx2 + (size_t)2 * kN * kC2;
  float* ss1 = (float*)(w + oSS1);
  float* sd1 = (float*)(w + oSD1);
  float* ss2 = (float*)(w + oSS2);
  float* sd2 = (float*)(w + oSD2);

  hipMemsetAsync(d_ws, 0, zEnd, stream);

  build_bits<<<(E + 255) / 256, 256, 0, stream>>>(ei, E, rowbits, colbitsT);
  a2_tiled<<<dim3(kN / 64, kN / 64), 256, 0, stream>>>(rowbits, colbitsT, A2, colbits2T);
  a3_dense<<<kN, 256, 0, stream>>>(rowbits, A2, A3u, invr);
  transpose_motif<<<dim3(kN / 64, kN / 64), 256, 0, stream>>>(A3u, invr, motifT);

  gemm1<<<dim3(kC1 / 64, kN / 64, 2), 256, 0, stream>>>(x, l1w, hx1, l1as, l1ad, ss1, sd1);
  agg_l1<<<kN, 256, 0, stream>>>(hx1, ss1, sd1, motifT, colbitsT, colbits2T,
                                 l1ha, l1b, hbuf);

  gemm2<<<dim3(1, kN / 64, 3), 256, 0, stream>>>(hbuf, l2w, l2rw, hx2,
                                                 l2as, l2ad, ss2, sd2);
  agg_l2<<<kN, 256, 0, stream>>>(hx2, ss2, sd2, motifT, colbitsT, colbits2T,
                                 l2ha, res, lns, lnb, l2b, (float*)d_out);
}